// Round 1
// baseline (4021.291 us; speedup 1.0000x reference)
//
#include <hip/hip_runtime.h>

// LightGCN forward: two gather-scale-scatter-sum propagations.
// Baseline: edge-parallel with float atomics.
//
// Sizes (fixed by the problem):
//   x:    [100000, 128] f32
//   src0/dst0/ew0: [1600000]
//   src1/dst1/ew1: [800000]
//   h:    [50000, 128] f32   (workspace)
//   out:  [25000, 128] f32

#define DIMS 128
#define COLG 32  // 128 / 4 float4-groups per edge

__global__ __launch_bounds__(256) void prop_atomic(
    const float* __restrict__ x,
    const int* __restrict__ src,
    const int* __restrict__ dst,
    const float* __restrict__ ew,
    float* __restrict__ out,
    int E) {
  long long idx = (long long)blockIdx.x * blockDim.x + threadIdx.x;
  long long total = (long long)E * COLG;
  if (idx >= total) return;
  int e  = (int)(idx >> 5);   // edge id
  int cg = (int)(idx & 31);   // float4 group within the 128-wide row

  int s   = src[e];
  int d   = dst[e];
  float w = ew[e];

  const float4 v = *reinterpret_cast<const float4*>(x + (size_t)s * DIMS + cg * 4);
  float* o = out + (size_t)d * DIMS + cg * 4;
  atomicAdd(o + 0, v.x * w);
  atomicAdd(o + 1, v.y * w);
  atomicAdd(o + 2, v.z * w);
  atomicAdd(o + 3, v.w * w);
}

extern "C" void kernel_launch(void* const* d_in, const int* in_sizes, int n_in,
                              void* d_out, int out_size, void* d_ws, size_t ws_size,
                              hipStream_t stream) {
  const float* x    = (const float*)d_in[0];
  const int*   src0 = (const int*)d_in[1];
  const int*   dst0 = (const int*)d_in[2];
  const float* ew0  = (const float*)d_in[3];
  const int*   src1 = (const int*)d_in[4];
  const int*   dst1 = (const int*)d_in[5];
  const float* ew1  = (const float*)d_in[6];

  const int E0 = in_sizes[1];       // 1600000
  const int E1 = in_sizes[4];       // 800000
  const int N_DST0 = 50000;
  const int N_DST1 = 25000;

  float* h   = (float*)d_ws;                         // 50000*128*4 = 25.6 MB
  float* out = (float*)d_out;                        // 25000*128*4 = 12.8 MB

  // Zero accumulators (graph-capture-safe async memsets on the stream).
  hipMemsetAsync(h,   0, (size_t)N_DST0 * DIMS * sizeof(float), stream);
  hipMemsetAsync(out, 0, (size_t)N_DST1 * DIMS * sizeof(float), stream);

  // Stage 1: h[dst0] += x[src0] * ew0
  {
    long long total = (long long)E0 * COLG;
    int blocks = (int)((total + 255) / 256);
    prop_atomic<<<blocks, 256, 0, stream>>>(x, src0, dst0, ew0, h, E0);
  }
  // Stage 2: out[dst1] += h[src1] * ew1
  {
    long long total = (long long)E1 * COLG;
    int blocks = (int)((total + 255) / 256);
    prop_atomic<<<blocks, 256, 0, stream>>>(h, src1, dst1, ew1, out, E1);
  }
}

// Round 2
// 650.702 us; speedup vs baseline: 6.1799x; 6.1799x over previous
//
#include <hip/hip_runtime.h>

// LightGCN forward: two gather-scale-scatter-sum propagations.
// Round 2: destination-centric CSR (built on device each call) + one wave
// per destination row with register accumulation. No f32 atomics.
//
// Sizes (fixed by the problem):
//   x:    [100000, 128] f32
//   src0/dst0/ew0: [1600000]
//   src1/dst1/ew1: [800000]
//   h:    [50000, 128] f32   (workspace)
//   out:  [25000, 128] f32

#define DIMS 128

// ---------------------------------------------------------------- CSR build

__global__ __launch_bounds__(256) void count_dst(
    const int* __restrict__ dst, int* __restrict__ counts, int E) {
  int e = blockIdx.x * blockDim.x + threadIdx.x;
  if (e < E) atomicAdd(&counts[dst[e]], 1);
}

// Single-block exclusive scan of `counts[0..n)` -> offs[0..n], cursors[0..n).
__global__ __launch_bounds__(1024) void scan_block(
    const int* __restrict__ counts, int* __restrict__ offs,
    int* __restrict__ cursors, int n) {
  __shared__ int part[1024];
  const int t = threadIdx.x;
  const int chunk = (n + 1023) >> 10;
  const int beg = t * chunk;
  const int end = min(beg + chunk, n);
  int s = 0;
  for (int i = beg; i < end; ++i) s += counts[i];
  part[t] = s;
  __syncthreads();
  // Hillis-Steele inclusive scan over the 1024 partials.
  for (int off = 1; off < 1024; off <<= 1) {
    int v = (t >= off) ? part[t - off] : 0;
    __syncthreads();
    part[t] += v;
    __syncthreads();
  }
  int excl = (t == 0) ? 0 : part[t - 1];
  for (int i = beg; i < end; ++i) {
    offs[i] = excl;
    cursors[i] = excl;
    excl += counts[i];
  }
  if (t == 0) offs[n] = part[1023];
}

// Permute edge payload (src id, weight) into dst-bucketed order.
__global__ __launch_bounds__(256) void scatter_edges(
    const int* __restrict__ src, const int* __restrict__ dst,
    const float* __restrict__ ew, int* __restrict__ cursors,
    int* __restrict__ srcp, float* __restrict__ wp, int E) {
  int e = blockIdx.x * blockDim.x + threadIdx.x;
  if (e >= E) return;
  int pos = atomicAdd(&cursors[dst[e]], 1);
  srcp[pos] = src[e];
  wp[pos] = ew[e];
}

// ------------------------------------------------------------- gather stage
// One 64-lane wave per destination row; lane owns float2 (2 cols).
__global__ __launch_bounds__(256) void gather_rows(
    const float* __restrict__ x, const int* __restrict__ offs,
    const int* __restrict__ srcp, const float* __restrict__ wp,
    float* __restrict__ out, int n_dst) {
  int wid = blockIdx.x * (blockDim.x >> 6) + (threadIdx.x >> 6);
  int lane = threadIdx.x & 63;
  if (wid >= n_dst) return;
  const int beg = offs[wid];
  const int end = offs[wid + 1];
  float2 acc = make_float2(0.f, 0.f);
  int j = beg;
  for (; j + 1 < end; j += 2) {
    int s0 = srcp[j];
    int s1 = srcp[j + 1];
    float w0 = wp[j];
    float w1 = wp[j + 1];
    float2 v0 = *reinterpret_cast<const float2*>(x + (size_t)s0 * DIMS + lane * 2);
    float2 v1 = *reinterpret_cast<const float2*>(x + (size_t)s1 * DIMS + lane * 2);
    acc.x += v0.x * w0;
    acc.y += v0.y * w0;
    acc.x += v1.x * w1;
    acc.y += v1.y * w1;
  }
  if (j < end) {
    int s0 = srcp[j];
    float w0 = wp[j];
    float2 v0 = *reinterpret_cast<const float2*>(x + (size_t)s0 * DIMS + lane * 2);
    acc.x += v0.x * w0;
    acc.y += v0.y * w0;
  }
  *reinterpret_cast<float2*>(out + (size_t)wid * DIMS + lane * 2) = acc;
}

// ------------------------------------------------- fallback (round-1 path)
#define COLG 32
__global__ __launch_bounds__(256) void prop_atomic(
    const float* __restrict__ x, const int* __restrict__ src,
    const int* __restrict__ dst, const float* __restrict__ ew,
    float* __restrict__ out, int E) {
  long long idx = (long long)blockIdx.x * blockDim.x + threadIdx.x;
  long long total = (long long)E * COLG;
  if (idx >= total) return;
  int e = (int)(idx >> 5);
  int cg = (int)(idx & 31);
  int s = src[e];
  int d = dst[e];
  float w = ew[e];
  const float4 v = *reinterpret_cast<const float4*>(x + (size_t)s * DIMS + cg * 4);
  float* o = out + (size_t)d * DIMS + cg * 4;
  atomicAdd(o + 0, v.x * w);
  atomicAdd(o + 1, v.y * w);
  atomicAdd(o + 2, v.z * w);
  atomicAdd(o + 3, v.w * w);
}

// --------------------------------------------------------------- launcher

static inline size_t align_up(size_t v, size_t a) { return (v + a - 1) / a * a; }

extern "C" void kernel_launch(void* const* d_in, const int* in_sizes, int n_in,
                              void* d_out, int out_size, void* d_ws, size_t ws_size,
                              hipStream_t stream) {
  const float* x    = (const float*)d_in[0];
  const int*   src0 = (const int*)d_in[1];
  const int*   dst0 = (const int*)d_in[2];
  const float* ew0  = (const float*)d_in[3];
  const int*   src1 = (const int*)d_in[4];
  const int*   dst1 = (const int*)d_in[5];
  const float* ew1  = (const float*)d_in[6];

  const int E0 = in_sizes[1];   // 1600000
  const int E1 = in_sizes[4];   // 800000
  const int N_DST0 = 50000;
  const int N_DST1 = 25000;

  float* out = (float*)d_out;

  // --- workspace layout ---
  char* ws = (char*)d_ws;
  size_t off = 0;
  float* h = (float*)(ws + off);            off = align_up(off + (size_t)N_DST0 * DIMS * 4, 16);
  int* counts0  = (int*)(ws + off);         off = align_up(off + (size_t)N_DST0 * 4, 16);
  int* offs0    = (int*)(ws + off);         off = align_up(off + ((size_t)N_DST0 + 1) * 4, 16);
  int* cursors0 = (int*)(ws + off);         off = align_up(off + (size_t)N_DST0 * 4, 16);
  int* srcp0    = (int*)(ws + off);         off = align_up(off + (size_t)E0 * 4, 16);
  float* wp0    = (float*)(ws + off);       off = align_up(off + (size_t)E0 * 4, 16);
  int* counts1  = (int*)(ws + off);         off = align_up(off + (size_t)N_DST1 * 4, 16);
  int* offs1    = (int*)(ws + off);         off = align_up(off + ((size_t)N_DST1 + 1) * 4, 16);
  int* cursors1 = (int*)(ws + off);         off = align_up(off + (size_t)N_DST1 * 4, 16);
  int* srcp1    = (int*)(ws + off);         off = align_up(off + (size_t)E1 * 4, 16);
  float* wp1    = (float*)(ws + off);       off = align_up(off + (size_t)E1 * 4, 16);
  const size_t needed = off;

  if (ws_size < needed) {
    // Fallback: round-1 atomic path (needs only h).
    hipMemsetAsync(h, 0, (size_t)N_DST0 * DIMS * 4, stream);
    hipMemsetAsync(out, 0, (size_t)N_DST1 * DIMS * 4, stream);
    long long t0 = (long long)E0 * COLG;
    prop_atomic<<<(int)((t0 + 255) / 256), 256, 0, stream>>>(x, src0, dst0, ew0, h, E0);
    long long t1 = (long long)E1 * COLG;
    prop_atomic<<<(int)((t1 + 255) / 256), 256, 0, stream>>>(h, src1, dst1, ew1, out, E1);
    return;
  }

  // --- stage 1: h[dst0] += x[src0] * ew0 ---
  hipMemsetAsync(counts0, 0, (size_t)N_DST0 * 4, stream);
  count_dst<<<(E0 + 255) / 256, 256, 0, stream>>>(dst0, counts0, E0);
  scan_block<<<1, 1024, 0, stream>>>(counts0, offs0, cursors0, N_DST0);
  scatter_edges<<<(E0 + 255) / 256, 256, 0, stream>>>(src0, dst0, ew0, cursors0,
                                                      srcp0, wp0, E0);
  gather_rows<<<(N_DST0 + 3) / 4, 256, 0, stream>>>(x, offs0, srcp0, wp0, h, N_DST0);

  // --- stage 2: out[dst1] += h[src1] * ew1 ---
  hipMemsetAsync(counts1, 0, (size_t)N_DST1 * 4, stream);
  count_dst<<<(E1 + 255) / 256, 256, 0, stream>>>(dst1, counts1, E1);
  scan_block<<<1, 1024, 0, stream>>>(counts1, offs1, cursors1, N_DST1);
  scatter_edges<<<(E1 + 255) / 256, 256, 0, stream>>>(src1, dst1, ew1, cursors1,
                                                      srcp1, wp1, E1);
  gather_rows<<<(N_DST1 + 3) / 4, 256, 0, stream>>>(h, offs1, srcp1, wp1, out, N_DST1);
}

// Round 3
// 606.764 us; speedup vs baseline: 6.6274x; 1.0724x over previous
//
#include <hip/hip_runtime.h>

// LightGCN forward: two gather-scale-scatter-sum propagations.
// Round 3: CSR build with interleaved int2 payload (src, weight) -> one 8B
// random store per edge in scatter (was 2x 4B to distant arrays = 11x write
// amplification). Gather unrolled x4 for more memory-level parallelism.
//
// Sizes (fixed by the problem):
//   x:    [100000, 128] f32
//   src0/dst0/ew0: [1600000]
//   src1/dst1/ew1: [800000]
//   h:    [50000, 128] f32   (workspace)
//   out:  [25000, 128] f32

#define DIMS 128

// ---------------------------------------------------------------- CSR build

__global__ __launch_bounds__(256) void count_dst(
    const int* __restrict__ dst, int* __restrict__ counts, int E) {
  int e = blockIdx.x * blockDim.x + threadIdx.x;
  if (e < E) atomicAdd(&counts[dst[e]], 1);
}

// Single-block exclusive scan of `counts[0..n)` -> offs[0..n], cursors[0..n).
__global__ __launch_bounds__(1024) void scan_block(
    const int* __restrict__ counts, int* __restrict__ offs,
    int* __restrict__ cursors, int n) {
  __shared__ int part[1024];
  const int t = threadIdx.x;
  const int chunk = (n + 1023) >> 10;
  const int beg = t * chunk;
  const int end = min(beg + chunk, n);
  int s = 0;
  for (int i = beg; i < end; ++i) s += counts[i];
  part[t] = s;
  __syncthreads();
  for (int off = 1; off < 1024; off <<= 1) {
    int v = (t >= off) ? part[t - off] : 0;
    __syncthreads();
    part[t] += v;
    __syncthreads();
  }
  int excl = (t == 0) ? 0 : part[t - 1];
  for (int i = beg; i < end; ++i) {
    offs[i] = excl;
    cursors[i] = excl;
    excl += counts[i];
  }
  if (t == 0) offs[n] = part[1023];
}

// Permute edge payload (src id, weight) into dst-bucketed order.
// Interleaved int2 payload: ONE 8B store per edge.
__global__ __launch_bounds__(256) void scatter_edges(
    const int* __restrict__ src, const int* __restrict__ dst,
    const float* __restrict__ ew, int* __restrict__ cursors,
    int2* __restrict__ payl, int E) {
  int e = blockIdx.x * blockDim.x + threadIdx.x;
  if (e >= E) return;
  int pos = atomicAdd(&cursors[dst[e]], 1);
  payl[pos] = make_int2(src[e], __float_as_int(ew[e]));
}

// ------------------------------------------------------------- gather stage
// One 64-lane wave per destination row; lane owns float2 (2 cols).
// Unroll x4 with two accumulator pairs for memory-level parallelism.
__global__ __launch_bounds__(256) void gather_rows(
    const float* __restrict__ x, const int* __restrict__ offs,
    const int2* __restrict__ payl, float* __restrict__ out, int n_dst) {
  int wid = blockIdx.x * (blockDim.x >> 6) + (threadIdx.x >> 6);
  int lane = threadIdx.x & 63;
  if (wid >= n_dst) return;
  const int beg = offs[wid];
  const int end = offs[wid + 1];
  float2 a0 = make_float2(0.f, 0.f);
  float2 a1 = make_float2(0.f, 0.f);
  int j = beg;
  for (; j + 3 < end; j += 4) {
    int2 p0 = payl[j];
    int2 p1 = payl[j + 1];
    int2 p2 = payl[j + 2];
    int2 p3 = payl[j + 3];
    float2 v0 = *reinterpret_cast<const float2*>(x + (size_t)p0.x * DIMS + lane * 2);
    float2 v1 = *reinterpret_cast<const float2*>(x + (size_t)p1.x * DIMS + lane * 2);
    float2 v2 = *reinterpret_cast<const float2*>(x + (size_t)p2.x * DIMS + lane * 2);
    float2 v3 = *reinterpret_cast<const float2*>(x + (size_t)p3.x * DIMS + lane * 2);
    float w0 = __int_as_float(p0.y);
    float w1 = __int_as_float(p1.y);
    float w2 = __int_as_float(p2.y);
    float w3 = __int_as_float(p3.y);
    a0.x += v0.x * w0; a0.y += v0.y * w0;
    a1.x += v1.x * w1; a1.y += v1.y * w1;
    a0.x += v2.x * w2; a0.y += v2.y * w2;
    a1.x += v3.x * w3; a1.y += v3.y * w3;
  }
  for (; j < end; ++j) {
    int2 p0 = payl[j];
    float w0 = __int_as_float(p0.y);
    float2 v0 = *reinterpret_cast<const float2*>(x + (size_t)p0.x * DIMS + lane * 2);
    a0.x += v0.x * w0; a0.y += v0.y * w0;
  }
  float2 acc = make_float2(a0.x + a1.x, a0.y + a1.y);
  *reinterpret_cast<float2*>(out + (size_t)wid * DIMS + lane * 2) = acc;
}

// ------------------------------------------------- fallback (round-1 path)
#define COLG 32
__global__ __launch_bounds__(256) void prop_atomic(
    const float* __restrict__ x, const int* __restrict__ src,
    const int* __restrict__ dst, const float* __restrict__ ew,
    float* __restrict__ out, int E) {
  long long idx = (long long)blockIdx.x * blockDim.x + threadIdx.x;
  long long total = (long long)E * COLG;
  if (idx >= total) return;
  int e = (int)(idx >> 5);
  int cg = (int)(idx & 31);
  int s = src[e];
  int d = dst[e];
  float w = ew[e];
  const float4 v = *reinterpret_cast<const float4*>(x + (size_t)s * DIMS + cg * 4);
  float* o = out + (size_t)d * DIMS + cg * 4;
  atomicAdd(o + 0, v.x * w);
  atomicAdd(o + 1, v.y * w);
  atomicAdd(o + 2, v.z * w);
  atomicAdd(o + 3, v.w * w);
}

// --------------------------------------------------------------- launcher

static inline size_t align_up(size_t v, size_t a) { return (v + a - 1) / a * a; }

extern "C" void kernel_launch(void* const* d_in, const int* in_sizes, int n_in,
                              void* d_out, int out_size, void* d_ws, size_t ws_size,
                              hipStream_t stream) {
  const float* x    = (const float*)d_in[0];
  const int*   src0 = (const int*)d_in[1];
  const int*   dst0 = (const int*)d_in[2];
  const float* ew0  = (const float*)d_in[3];
  const int*   src1 = (const int*)d_in[4];
  const int*   dst1 = (const int*)d_in[5];
  const float* ew1  = (const float*)d_in[6];

  const int E0 = in_sizes[1];   // 1600000
  const int E1 = in_sizes[4];   // 800000
  const int N_DST0 = 50000;
  const int N_DST1 = 25000;

  float* out = (float*)d_out;

  // --- workspace layout ---
  char* ws = (char*)d_ws;
  size_t off = 0;
  float* h = (float*)(ws + off);            off = align_up(off + (size_t)N_DST0 * DIMS * 4, 16);
  int* counts0  = (int*)(ws + off);         off = align_up(off + (size_t)N_DST0 * 4, 16);
  int* offs0    = (int*)(ws + off);         off = align_up(off + ((size_t)N_DST0 + 1) * 4, 16);
  int* cursors0 = (int*)(ws + off);         off = align_up(off + (size_t)N_DST0 * 4, 16);
  int2* payl0   = (int2*)(ws + off);        off = align_up(off + (size_t)E0 * 8, 16);
  int* counts1  = (int*)(ws + off);         off = align_up(off + (size_t)N_DST1 * 4, 16);
  int* offs1    = (int*)(ws + off);         off = align_up(off + ((size_t)N_DST1 + 1) * 4, 16);
  int* cursors1 = (int*)(ws + off);         off = align_up(off + (size_t)N_DST1 * 4, 16);
  int2* payl1   = (int2*)(ws + off);        off = align_up(off + (size_t)E1 * 8, 16);
  const size_t needed = off;

  if (ws_size < needed) {
    // Fallback: round-1 atomic path (needs only h).
    hipMemsetAsync(h, 0, (size_t)N_DST0 * DIMS * 4, stream);
    hipMemsetAsync(out, 0, (size_t)N_DST1 * DIMS * 4, stream);
    long long t0 = (long long)E0 * COLG;
    prop_atomic<<<(int)((t0 + 255) / 256), 256, 0, stream>>>(x, src0, dst0, ew0, h, E0);
    long long t1 = (long long)E1 * COLG;
    prop_atomic<<<(int)((t1 + 255) / 256), 256, 0, stream>>>(h, src1, dst1, ew1, out, E1);
    return;
  }

  // --- stage 1: h[dst0] += x[src0] * ew0 ---
  hipMemsetAsync(counts0, 0, (size_t)N_DST0 * 4, stream);
  count_dst<<<(E0 + 255) / 256, 256, 0, stream>>>(dst0, counts0, E0);
  scan_block<<<1, 1024, 0, stream>>>(counts0, offs0, cursors0, N_DST0);
  scatter_edges<<<(E0 + 255) / 256, 256, 0, stream>>>(src0, dst0, ew0, cursors0,
                                                      payl0, E0);
  gather_rows<<<(N_DST0 + 3) / 4, 256, 0, stream>>>(x, offs0, payl0, h, N_DST0);

  // --- stage 2: out[dst1] += h[src1] * ew1 ---
  hipMemsetAsync(counts1, 0, (size_t)N_DST1 * 4, stream);
  count_dst<<<(E1 + 255) / 256, 256, 0, stream>>>(dst1, counts1, E1);
  scan_block<<<1, 1024, 0, stream>>>(counts1, offs1, cursors1, N_DST1);
  scatter_edges<<<(E1 + 255) / 256, 256, 0, stream>>>(src1, dst1, ew1, cursors1,
                                                      payl1, E1);
  gather_rows<<<(N_DST1 + 3) / 4, 256, 0, stream>>>(h, offs1, payl1, out, N_DST1);
}

// Round 4
// 539.732 us; speedup vs baseline: 7.4505x; 1.1242x over previous
//
#include <hip/hip_runtime.h>

// LightGCN forward: two gather-scale-scatter-sum propagations.
// Round 4: per-XCD privatized CSR build. MI355X's 8 per-XCD L2s are not
// coherent, so round-3's dst-tail appends (and cursor/count atomic lines)
// ping-ponged lines across XCDs -> 64B writeback per 8B append (101 MB for a
// 12.8 MB payload). Here each XCD appends into its own contiguous payload
// region (counts/cursors laid out xcd-major), so every hot line is owned by
// one L2. Gather walks 8 contiguous sub-segments per destination row.
//
// Sizes (fixed by the problem):
//   x:    [100000, 128] f32
//   src0/dst0/ew0: [1600000]
//   src1/dst1/ew1: [800000]
//   h:    [50000, 128] f32   (workspace)
//   out:  [25000, 128] f32

#define DIMS 128
#define NXCD 8

__device__ __forceinline__ int xcc_id() {
  unsigned x;
  asm volatile("s_getreg_b32 %0, hwreg(HW_REG_XCC_ID)" : "=s"(x));
  return (int)(x & (NXCD - 1));
}

// ---------------------------------------------------------------- CSR build

// counts laid out [NXCD][N]: each XCD's atomics hit its own 4*N-byte slice.
__global__ __launch_bounds__(256) void count_dst_x(
    const int* __restrict__ dst, int* __restrict__ counts, int E, int N) {
  int x = xcc_id();
  int e = blockIdx.x * blockDim.x + threadIdx.x;
  if (e < E) atomicAdd(&counts[x * N + dst[e]], 1);
}

// Per-segment (per-XCD slice) exclusive scan; 8 blocks, block = segment.
// Writes cursorL (local exclusive prefix) and totals[seg].
__global__ __launch_bounds__(1024) void scan_seg(
    const int* __restrict__ counts, int* __restrict__ cursorL,
    int* __restrict__ totals, int N) {
  __shared__ int part[1024];
  const int base = blockIdx.x * N;
  const int t = threadIdx.x;
  const int chunk = (N + 1023) >> 10;
  const int beg = t * chunk;
  const int end = min(beg + chunk, N);
  int s = 0;
  for (int i = beg; i < end; ++i) s += counts[base + i];
  part[t] = s;
  __syncthreads();
  for (int off = 1; off < 1024; off <<= 1) {
    int v = (t >= off) ? part[t - off] : 0;
    __syncthreads();
    part[t] += v;
    __syncthreads();
  }
  int excl = (t == 0) ? 0 : part[t - 1];
  for (int i = beg; i < end; ++i) {
    cursorL[base + i] = excl;
    excl += counts[base + i];
  }
  if (t == 1023) totals[blockIdx.x] = part[1023];
}

// Tiny exclusive scan of the 8 segment totals -> per-XCD payload base.
__global__ void scan_base(const int* __restrict__ totals,
                          int* __restrict__ xcdBase) {
  if (threadIdx.x == 0 && blockIdx.x == 0) {
    int run = 0;
    for (int i = 0; i < NXCD; ++i) { xcdBase[i] = run; run += totals[i]; }
  }
}

// Append edge payload into this XCD's private region. After this kernel,
// cursorL[x*N+d] == local END of (x,d)'s sub-segment (gather uses end-count).
__global__ __launch_bounds__(256) void scatter_edges_x(
    const int* __restrict__ src, const int* __restrict__ dst,
    const float* __restrict__ ew, int* __restrict__ cursorL,
    const int* __restrict__ xcdBase, int2* __restrict__ payl, int E, int N) {
  int x = xcc_id();
  int base = xcdBase[x];
  int e = blockIdx.x * blockDim.x + threadIdx.x;
  if (e >= E) return;
  int pos = base + atomicAdd(&cursorL[x * N + dst[e]], 1);
  payl[pos] = make_int2(src[e], __float_as_int(ew[e]));
}

// ------------------------------------------------------------- gather stage
// One 64-lane wave per destination row; lane owns float2 (2 cols).
// Walks the row's 8 per-XCD sub-segments (each contiguous).
__global__ __launch_bounds__(256) void gather_rows_x(
    const float* __restrict__ feat, const int* __restrict__ cursorEnd,
    const int* __restrict__ counts, const int* __restrict__ xcdBase,
    const int2* __restrict__ payl, float* __restrict__ out, int n_dst, int N) {
  int wid = blockIdx.x * (blockDim.x >> 6) + (threadIdx.x >> 6);
  int lane = threadIdx.x & 63;
  if (wid >= n_dst) return;
  float2 a0 = make_float2(0.f, 0.f);
  float2 a1 = make_float2(0.f, 0.f);
  for (int x = 0; x < NXCD; ++x) {
    int cnt = counts[x * N + wid];
    int end = xcdBase[x] + cursorEnd[x * N + wid];
    int j = end - cnt;
    for (; j + 1 < end; j += 2) {
      int2 p0 = payl[j];
      int2 p1 = payl[j + 1];
      float2 v0 = *reinterpret_cast<const float2*>(feat + (size_t)p0.x * DIMS + lane * 2);
      float2 v1 = *reinterpret_cast<const float2*>(feat + (size_t)p1.x * DIMS + lane * 2);
      float w0 = __int_as_float(p0.y);
      float w1 = __int_as_float(p1.y);
      a0.x += v0.x * w0; a0.y += v0.y * w0;
      a1.x += v1.x * w1; a1.y += v1.y * w1;
    }
    if (j < end) {
      int2 p0 = payl[j];
      float w0 = __int_as_float(p0.y);
      float2 v0 = *reinterpret_cast<const float2*>(feat + (size_t)p0.x * DIMS + lane * 2);
      a0.x += v0.x * w0; a0.y += v0.y * w0;
    }
  }
  float2 acc = make_float2(a0.x + a1.x, a0.y + a1.y);
  *reinterpret_cast<float2*>(out + (size_t)wid * DIMS + lane * 2) = acc;
}

// ------------------------------------------------- fallback (round-1 path)
#define COLG 32
__global__ __launch_bounds__(256) void prop_atomic(
    const float* __restrict__ x, const int* __restrict__ src,
    const int* __restrict__ dst, const float* __restrict__ ew,
    float* __restrict__ out, int E) {
  long long idx = (long long)blockIdx.x * blockDim.x + threadIdx.x;
  long long total = (long long)E * COLG;
  if (idx >= total) return;
  int e = (int)(idx >> 5);
  int cg = (int)(idx & 31);
  int s = src[e];
  int d = dst[e];
  float w = ew[e];
  const float4 v = *reinterpret_cast<const float4*>(x + (size_t)s * DIMS + cg * 4);
  float* o = out + (size_t)d * DIMS + cg * 4;
  atomicAdd(o + 0, v.x * w);
  atomicAdd(o + 1, v.y * w);
  atomicAdd(o + 2, v.z * w);
  atomicAdd(o + 3, v.w * w);
}

// --------------------------------------------------------------- launcher

static inline size_t align_up(size_t v, size_t a) { return (v + a - 1) / a * a; }

extern "C" void kernel_launch(void* const* d_in, const int* in_sizes, int n_in,
                              void* d_out, int out_size, void* d_ws, size_t ws_size,
                              hipStream_t stream) {
  const float* x    = (const float*)d_in[0];
  const int*   src0 = (const int*)d_in[1];
  const int*   dst0 = (const int*)d_in[2];
  const float* ew0  = (const float*)d_in[3];
  const int*   src1 = (const int*)d_in[4];
  const int*   dst1 = (const int*)d_in[5];
  const float* ew1  = (const float*)d_in[6];

  const int E0 = in_sizes[1];   // 1600000
  const int E1 = in_sizes[4];   // 800000
  const int N_DST0 = 50000;
  const int N_DST1 = 25000;

  float* out = (float*)d_out;

  // --- workspace layout ---
  char* ws = (char*)d_ws;
  size_t off = 0;
  float* h = (float*)(ws + off);         off = align_up(off + (size_t)N_DST0 * DIMS * 4, 16);
  int* counts0  = (int*)(ws + off);      off = align_up(off + (size_t)NXCD * N_DST0 * 4, 16);
  int* cursor0  = (int*)(ws + off);      off = align_up(off + (size_t)NXCD * N_DST0 * 4, 16);
  int* totals0  = (int*)(ws + off);      off = align_up(off + (size_t)NXCD * 4, 16);
  int* xbase0   = (int*)(ws + off);      off = align_up(off + (size_t)NXCD * 4, 16);
  int2* payl0   = (int2*)(ws + off);     off = align_up(off + (size_t)E0 * 8, 16);
  int* counts1  = (int*)(ws + off);      off = align_up(off + (size_t)NXCD * N_DST1 * 4, 16);
  int* cursor1  = (int*)(ws + off);      off = align_up(off + (size_t)NXCD * N_DST1 * 4, 16);
  int* totals1  = (int*)(ws + off);      off = align_up(off + (size_t)NXCD * 4, 16);
  int* xbase1   = (int*)(ws + off);      off = align_up(off + (size_t)NXCD * 4, 16);
  int2* payl1   = (int2*)(ws + off);     off = align_up(off + (size_t)E1 * 8, 16);
  const size_t needed = off;

  if (ws_size < needed) {
    // Fallback: round-1 atomic path (needs only h).
    hipMemsetAsync(h, 0, (size_t)N_DST0 * DIMS * 4, stream);
    hipMemsetAsync(out, 0, (size_t)N_DST1 * DIMS * 4, stream);
    long long t0 = (long long)E0 * COLG;
    prop_atomic<<<(int)((t0 + 255) / 256), 256, 0, stream>>>(x, src0, dst0, ew0, h, E0);
    long long t1 = (long long)E1 * COLG;
    prop_atomic<<<(int)((t1 + 255) / 256), 256, 0, stream>>>(h, src1, dst1, ew1, out, E1);
    return;
  }

  // --- stage 1: h[dst0] += x[src0] * ew0 ---
  hipMemsetAsync(counts0, 0, (size_t)NXCD * N_DST0 * 4, stream);
  count_dst_x<<<(E0 + 255) / 256, 256, 0, stream>>>(dst0, counts0, E0, N_DST0);
  scan_seg<<<NXCD, 1024, 0, stream>>>(counts0, cursor0, totals0, N_DST0);
  scan_base<<<1, 64, 0, stream>>>(totals0, xbase0);
  scatter_edges_x<<<(E0 + 255) / 256, 256, 0, stream>>>(src0, dst0, ew0, cursor0,
                                                        xbase0, payl0, E0, N_DST0);
  gather_rows_x<<<(N_DST0 + 3) / 4, 256, 0, stream>>>(x, cursor0, counts0, xbase0,
                                                      payl0, h, N_DST0, N_DST0);

  // --- stage 2: out[dst1] += h[src1] * ew1 ---
  hipMemsetAsync(counts1, 0, (size_t)NXCD * N_DST1 * 4, stream);
  count_dst_x<<<(E1 + 255) / 256, 256, 0, stream>>>(dst1, counts1, E1, N_DST1);
  scan_seg<<<NXCD, 1024, 0, stream>>>(counts1, cursor1, totals1, N_DST1);
  scan_base<<<1, 64, 0, stream>>>(totals1, xbase1);
  scatter_edges_x<<<(E1 + 255) / 256, 256, 0, stream>>>(src1, dst1, ew1, cursor1,
                                                        xbase1, payl1, E1, N_DST1);
  gather_rows_x<<<(N_DST1 + 3) / 4, 256, 0, stream>>>(h, cursor1, counts1, xbase1,
                                                      payl1, out, N_DST1, N_DST1);
}

// Round 5
// 526.896 us; speedup vs baseline: 7.6320x; 1.0244x over previous
//
#include <hip/hip_runtime.h>

// LightGCN forward: two gather-scale-scatter-sum propagations.
// Round 5: bf16 feature gather. Round-4 profile: gather_rows is bytes-bound
// (FETCH 397 MB @ 3.0 TB/s effective, VALU 22%). Quantize x -> bf16 once per
// call (rows 512B -> 256B), gather bf16, accumulate f32, store intermediate h
// as bf16 (stage-2 gather also 256B rows). Keeps round-4's per-XCD privatized
// CSR build (scatter no longer hot).
//
// Sizes (fixed by the problem):
//   x:    [100000, 128] f32
//   src0/dst0/ew0: [1600000]
//   src1/dst1/ew1: [800000]
//   out:  [25000, 128] f32

#define DIMS 128
#define NXCD 8

__device__ __forceinline__ int xcc_id() {
  unsigned x;
  asm volatile("s_getreg_b32 %0, hwreg(HW_REG_XCC_ID)" : "=s"(x));
  return (int)(x & (NXCD - 1));
}

__device__ __forceinline__ unsigned pack_bf16(float a, float b) {
  unsigned ua = __float_as_uint(a);
  ua = (ua + 0x7fffu + ((ua >> 16) & 1u)) >> 16;     // RNE
  unsigned ub = __float_as_uint(b);
  ub = (ub + 0x7fffu + ((ub >> 16) & 1u)) >> 16;
  return ua | (ub << 16);
}

// ----------------------------------------------------------- f32 -> bf16x2
// Row = 64 uints; uint k holds cols {2k (lo), 2k+1 (hi)}.
__global__ __launch_bounds__(256) void cvt_rows(
    const float* __restrict__ in, unsigned* __restrict__ outb, long long n2) {
  long long t = (long long)blockIdx.x * blockDim.x + threadIdx.x;
  if (t >= n2) return;
  float2 v = *reinterpret_cast<const float2*>(in + t * 2);
  outb[t] = pack_bf16(v.x, v.y);
}

// ---------------------------------------------------------------- CSR build

// counts laid out [NXCD][N]: each XCD's atomics hit its own slice.
__global__ __launch_bounds__(256) void count_dst_x(
    const int* __restrict__ dst, int* __restrict__ counts, int E, int N) {
  int x = xcc_id();
  int e = blockIdx.x * blockDim.x + threadIdx.x;
  if (e < E) atomicAdd(&counts[x * N + dst[e]], 1);
}

// Per-segment (per-XCD slice) exclusive scan; 8 blocks, block = segment.
__global__ __launch_bounds__(1024) void scan_seg(
    const int* __restrict__ counts, int* __restrict__ cursorL,
    int* __restrict__ totals, int N) {
  __shared__ int part[1024];
  const int base = blockIdx.x * N;
  const int t = threadIdx.x;
  const int chunk = (N + 1023) >> 10;
  const int beg = t * chunk;
  const int end = min(beg + chunk, N);
  int s = 0;
  for (int i = beg; i < end; ++i) s += counts[base + i];
  part[t] = s;
  __syncthreads();
  for (int off = 1; off < 1024; off <<= 1) {
    int v = (t >= off) ? part[t - off] : 0;
    __syncthreads();
    part[t] += v;
    __syncthreads();
  }
  int excl = (t == 0) ? 0 : part[t - 1];
  for (int i = beg; i < end; ++i) {
    cursorL[base + i] = excl;
    excl += counts[base + i];
  }
  if (t == 1023) totals[blockIdx.x] = part[1023];
}

__global__ void scan_base(const int* __restrict__ totals,
                          int* __restrict__ xcdBase) {
  if (threadIdx.x == 0 && blockIdx.x == 0) {
    int run = 0;
    for (int i = 0; i < NXCD; ++i) { xcdBase[i] = run; run += totals[i]; }
  }
}

// Append edge payload into this XCD's private region. After this kernel,
// cursorL[x*N+d] == local END of (x,d)'s sub-segment.
__global__ __launch_bounds__(256) void scatter_edges_x(
    const int* __restrict__ src, const int* __restrict__ dst,
    const float* __restrict__ ew, int* __restrict__ cursorL,
    const int* __restrict__ xcdBase, int2* __restrict__ payl, int E, int N) {
  int x = xcc_id();
  int base = xcdBase[x];
  int e = blockIdx.x * blockDim.x + threadIdx.x;
  if (e >= E) return;
  int pos = base + atomicAdd(&cursorL[x * N + dst[e]], 1);
  payl[pos] = make_int2(src[e], __float_as_int(ew[e]));
}

// ------------------------------------------------------------- gather stage
// One 64-lane wave per destination row; lane owns 2 cols (one bf16x2 uint).
// Walks the row's 8 per-XCD sub-segments. OUT_BF16 selects h (bf16) vs out (f32).
template <bool OUT_BF16>
__global__ __launch_bounds__(256) void gather_rows_bf(
    const unsigned* __restrict__ feat, const int* __restrict__ cursorEnd,
    const int* __restrict__ counts, const int* __restrict__ xcdBase,
    const int2* __restrict__ payl, void* __restrict__ out, int n_dst, int N) {
  int wid = blockIdx.x * (blockDim.x >> 6) + (threadIdx.x >> 6);
  int lane = threadIdx.x & 63;
  if (wid >= n_dst) return;
  float2 a0 = make_float2(0.f, 0.f);
  float2 a1 = make_float2(0.f, 0.f);
  for (int x = 0; x < NXCD; ++x) {
    int cnt = counts[x * N + wid];
    int end = xcdBase[x] + cursorEnd[x * N + wid];
    int j = end - cnt;
    for (; j + 1 < end; j += 2) {
      int2 p0 = payl[j];
      int2 p1 = payl[j + 1];
      unsigned u0 = feat[(size_t)p0.x * 64 + lane];
      unsigned u1 = feat[(size_t)p1.x * 64 + lane];
      float w0 = __int_as_float(p0.y);
      float w1 = __int_as_float(p1.y);
      float lo0 = __uint_as_float(u0 << 16);
      float hi0 = __uint_as_float(u0 & 0xffff0000u);
      float lo1 = __uint_as_float(u1 << 16);
      float hi1 = __uint_as_float(u1 & 0xffff0000u);
      a0.x += lo0 * w0; a0.y += hi0 * w0;
      a1.x += lo1 * w1; a1.y += hi1 * w1;
    }
    if (j < end) {
      int2 p0 = payl[j];
      unsigned u0 = feat[(size_t)p0.x * 64 + lane];
      float w0 = __int_as_float(p0.y);
      a0.x += __uint_as_float(u0 << 16) * w0;
      a0.y += __uint_as_float(u0 & 0xffff0000u) * w0;
    }
  }
  float ax = a0.x + a1.x;
  float ay = a0.y + a1.y;
  if (OUT_BF16) {
    ((unsigned*)out)[(size_t)wid * 64 + lane] = pack_bf16(ax, ay);
  } else {
    *reinterpret_cast<float2*>((float*)out + (size_t)wid * DIMS + lane * 2) =
        make_float2(ax, ay);
  }
}

// ------------------------------------------------- fallback (round-1 path)
#define COLG 32
__global__ __launch_bounds__(256) void prop_atomic(
    const float* __restrict__ x, const int* __restrict__ src,
    const int* __restrict__ dst, const float* __restrict__ ew,
    float* __restrict__ out, int E) {
  long long idx = (long long)blockIdx.x * blockDim.x + threadIdx.x;
  long long total = (long long)E * COLG;
  if (idx >= total) return;
  int e = (int)(idx >> 5);
  int cg = (int)(idx & 31);
  int s = src[e];
  int d = dst[e];
  float w = ew[e];
  const float4 v = *reinterpret_cast<const float4*>(x + (size_t)s * DIMS + cg * 4);
  float* o = out + (size_t)d * DIMS + cg * 4;
  atomicAdd(o + 0, v.x * w);
  atomicAdd(o + 1, v.y * w);
  atomicAdd(o + 2, v.z * w);
  atomicAdd(o + 3, v.w * w);
}

// --------------------------------------------------------------- launcher

static inline size_t align_up(size_t v, size_t a) { return (v + a - 1) / a * a; }

extern "C" void kernel_launch(void* const* d_in, const int* in_sizes, int n_in,
                              void* d_out, int out_size, void* d_ws, size_t ws_size,
                              hipStream_t stream) {
  const float* x    = (const float*)d_in[0];
  const int*   src0 = (const int*)d_in[1];
  const int*   dst0 = (const int*)d_in[2];
  const float* ew0  = (const float*)d_in[3];
  const int*   src1 = (const int*)d_in[4];
  const int*   dst1 = (const int*)d_in[5];
  const float* ew1  = (const float*)d_in[6];

  const int N_SRC0 = in_sizes[0] / DIMS;  // 100000
  const int E0 = in_sizes[1];             // 1600000
  const int E1 = in_sizes[4];             // 800000
  const int N_DST0 = 50000;
  const int N_DST1 = 25000;

  float* out = (float*)d_out;

  // --- workspace layout ---
  char* ws = (char*)d_ws;
  size_t off = 0;
  unsigned* xb  = (unsigned*)(ws + off); off = align_up(off + (size_t)N_SRC0 * 64 * 4, 16);
  unsigned* hb  = (unsigned*)(ws + off); off = align_up(off + (size_t)N_DST0 * 64 * 4, 16);
  int* counts0  = (int*)(ws + off);      off = align_up(off + (size_t)NXCD * N_DST0 * 4, 16);
  int* cursor0  = (int*)(ws + off);      off = align_up(off + (size_t)NXCD * N_DST0 * 4, 16);
  int* totals0  = (int*)(ws + off);      off = align_up(off + (size_t)NXCD * 4, 16);
  int* xbase0   = (int*)(ws + off);      off = align_up(off + (size_t)NXCD * 4, 16);
  int2* payl0   = (int2*)(ws + off);     off = align_up(off + (size_t)E0 * 8, 16);
  int* counts1  = (int*)(ws + off);      off = align_up(off + (size_t)NXCD * N_DST1 * 4, 16);
  int* cursor1  = (int*)(ws + off);      off = align_up(off + (size_t)NXCD * N_DST1 * 4, 16);
  int* totals1  = (int*)(ws + off);      off = align_up(off + (size_t)NXCD * 4, 16);
  int* xbase1   = (int*)(ws + off);      off = align_up(off + (size_t)NXCD * 4, 16);
  int2* payl1   = (int2*)(ws + off);     off = align_up(off + (size_t)E1 * 8, 16);
  const size_t needed = off;

  if (ws_size < needed) {
    // Fallback: round-1 atomic path (h f32 reuses front of ws).
    float* h = (float*)d_ws;
    hipMemsetAsync(h, 0, (size_t)N_DST0 * DIMS * 4, stream);
    hipMemsetAsync(out, 0, (size_t)N_DST1 * DIMS * 4, stream);
    long long t0 = (long long)E0 * COLG;
    prop_atomic<<<(int)((t0 + 255) / 256), 256, 0, stream>>>(x, src0, dst0, ew0, h, E0);
    long long t1 = (long long)E1 * COLG;
    prop_atomic<<<(int)((t1 + 255) / 256), 256, 0, stream>>>(h, src1, dst1, ew1, out, E1);
    return;
  }

  // --- convert x to bf16 rows ---
  {
    long long n2 = (long long)N_SRC0 * 64;
    cvt_rows<<<(int)((n2 + 255) / 256), 256, 0, stream>>>(x, xb, n2);
  }

  // --- stage 1: hb[dst0] += xb[src0] * ew0 (bf16 in, bf16 out) ---
  hipMemsetAsync(counts0, 0, (size_t)NXCD * N_DST0 * 4, stream);
  count_dst_x<<<(E0 + 255) / 256, 256, 0, stream>>>(dst0, counts0, E0, N_DST0);
  scan_seg<<<NXCD, 1024, 0, stream>>>(counts0, cursor0, totals0, N_DST0);
  scan_base<<<1, 64, 0, stream>>>(totals0, xbase0);
  scatter_edges_x<<<(E0 + 255) / 256, 256, 0, stream>>>(src0, dst0, ew0, cursor0,
                                                        xbase0, payl0, E0, N_DST0);
  gather_rows_bf<true><<<(N_DST0 + 3) / 4, 256, 0, stream>>>(
      xb, cursor0, counts0, xbase0, payl0, (void*)hb, N_DST0, N_DST0);

  // --- stage 2: out[dst1] += hb[src1] * ew1 (bf16 in, f32 out) ---
  hipMemsetAsync(counts1, 0, (size_t)NXCD * N_DST1 * 4, stream);
  count_dst_x<<<(E1 + 255) / 256, 256, 0, stream>>>(dst1, counts1, E1, N_DST1);
  scan_seg<<<NXCD, 1024, 0, stream>>>(counts1, cursor1, totals1, N_DST1);
  scan_base<<<1, 64, 0, stream>>>(totals1, xbase1);
  scatter_edges_x<<<(E1 + 255) / 256, 256, 0, stream>>>(src1, dst1, ew1, cursor1,
                                                        xbase1, payl1, E1, N_DST1);
  gather_rows_bf<false><<<(N_DST1 + 3) / 4, 256, 0, stream>>>(
      hb, cursor1, counts1, xbase1, payl1, (void*)out, N_DST1, N_DST1);
}

// Round 6
// 463.855 us; speedup vs baseline: 8.6693x; 1.1359x over previous
//
#include <hip/hip_runtime.h>

// LightGCN forward: two gather-scale-scatter-sum propagations.
// Round 6: quad-gather (4 edges per wave-load: lane=(edge-slot r, 16B chunk c),
// uint4 loads, shfl_xor reduce) + precomputed per-row segment ranges + launch
// fusion (count+cvt, 16-block scan, fused scatter). Keeps round-4's per-XCD
// privatized CSR build and round-5's bf16 features.
//
// Sizes (fixed by the problem):
//   x:    [100000, 128] f32
//   src0/dst0/ew0: [1600000]
//   src1/dst1/ew1: [800000]
//   out:  [25000, 128] f32

#define DIMS 128
#define NXCD 8

__device__ __forceinline__ int xcc_id() {
  unsigned x;
  asm volatile("s_getreg_b32 %0, hwreg(HW_REG_XCC_ID)" : "=s"(x));
  return (int)(x & (NXCD - 1));
}

__device__ __forceinline__ unsigned pack_bf16(float a, float b) {
  unsigned ua = __float_as_uint(a);
  ua = (ua + 0x7fffu + ((ua >> 16) & 1u)) >> 16;     // RNE
  unsigned ub = __float_as_uint(b);
  ub = (ub + 0x7fffu + ((ub >> 16) & 1u)) >> 16;
  return ua | (ub << 16);
}

// --------------------------------------------- fused count (both) + cvt bf16
// Blocks [0, cntBlocks): per-XCD degree counting for stage0 then stage1.
// Blocks [cntBlocks, ...): f32 -> bf16x2 conversion of x.
__global__ __launch_bounds__(256) void count_cvt(
    const int* __restrict__ dst0, const int* __restrict__ dst1,
    int* __restrict__ counts, const float* __restrict__ xf,
    unsigned* __restrict__ xbf, int E0, int E1, int N0, int N1,
    int cntBlocks, long long n2) {
  if ((int)blockIdx.x < cntBlocks) {
    int e = blockIdx.x * 256 + threadIdx.x;
    int x = xcc_id();
    if (e < E0) {
      atomicAdd(&counts[x * N0 + dst0[e]], 1);
    } else if (e - E0 < E1) {
      atomicAdd(&counts[NXCD * N0 + x * N1 + dst1[e - E0]], 1);
    }
  } else {
    long long t = (long long)(blockIdx.x - cntBlocks) * 256 + threadIdx.x;
    if (t < n2) {
      float2 v = *reinterpret_cast<const float2*>(xf + t * 2);
      xbf[t] = pack_bf16(v.x, v.y);
    }
  }
}

// ------------------------------------- per-segment exclusive scan, 16 blocks
// Blocks 0..7: stage0 XCD slices (len N0); blocks 8..15: stage1 (len N1).
__global__ __launch_bounds__(1024) void scan_seg16(
    const int* __restrict__ counts, int* __restrict__ cursor,
    int* __restrict__ totals, int N0, int N1) {
  __shared__ int part[1024];
  const int b = blockIdx.x;
  const int N = (b < NXCD) ? N0 : N1;
  const int base = (b < NXCD) ? b * N0 : NXCD * N0 + (b - NXCD) * N1;
  const int t = threadIdx.x;
  const int chunk = (N + 1023) >> 10;
  const int beg = t * chunk;
  const int end = min(beg + chunk, N);
  int s = 0;
  for (int i = beg; i < end; ++i) s += counts[base + i];
  part[t] = s;
  __syncthreads();
  for (int off = 1; off < 1024; off <<= 1) {
    int v = (t >= off) ? part[t - off] : 0;
    __syncthreads();
    part[t] += v;
    __syncthreads();
  }
  int excl = (t == 0) ? 0 : part[t - 1];
  for (int i = beg; i < end; ++i) {
    cursor[base + i] = excl;
    excl += counts[base + i];
  }
  if (t == 1023) totals[b] = part[1023];
}

// ----------------------- materialize per-row global (beg,end) segment ranges
// range layout [row][8] -> one 64B line per destination row.
__global__ __launch_bounds__(256) void mkranges(
    const int* __restrict__ counts, const int* __restrict__ cursor,
    const int* __restrict__ totals, int2* __restrict__ range0,
    int2* __restrict__ range1, int N0, int N1) {
  int t = blockIdx.x * 256 + threadIdx.x;
  const int tot0 = N0 * NXCD;
  if (t < tot0) {
    int i = t >> 3, x = t & 7;
    int xb = 0;
    for (int k = 0; k < x; ++k) xb += totals[k];
    int idx = x * N0 + i;
    int beg = xb + cursor[idx];
    range0[t] = make_int2(beg, beg + counts[idx]);
  } else if (t - tot0 < N1 * NXCD) {
    int t2 = t - tot0;
    int i = t2 >> 3, x = t2 & 7;
    int xb = 0;
    for (int k = 0; k < x; ++k) xb += totals[NXCD + k];
    int idx = NXCD * N0 + x * N1 + i;
    int beg = xb + cursor[idx];
    range1[t2] = make_int2(beg, beg + counts[idx]);
  }
}

// ---------------------------------------- fused scatter (both stages), XCD-local
__global__ __launch_bounds__(256) void scatter_both(
    const int* __restrict__ src0, const int* __restrict__ dst0,
    const float* __restrict__ ew0, const int* __restrict__ src1,
    const int* __restrict__ dst1, const float* __restrict__ ew1,
    int* __restrict__ cursor, const int* __restrict__ totals,
    int2* __restrict__ payl0, int2* __restrict__ payl1,
    int E0, int E1, int N0, int N1) {
  int e = blockIdx.x * 256 + threadIdx.x;
  int x = xcc_id();
  if (e < E0) {
    int xb = 0;
    for (int k = 0; k < x; ++k) xb += totals[k];
    int pos = xb + atomicAdd(&cursor[x * N0 + dst0[e]], 1);
    payl0[pos] = make_int2(src0[e], __float_as_int(ew0[e]));
  } else if (e - E0 < E1) {
    int e1 = e - E0;
    int xb = 0;
    for (int k = 0; k < x; ++k) xb += totals[NXCD + k];
    int pos = xb + atomicAdd(&cursor[NXCD * N0 + x * N1 + dst1[e1]], 1);
    payl1[pos] = make_int2(src1[e1], __float_as_int(ew1[e1]));
  }
}

// ----------------------------------------------------------- quad gather
// One 64-lane wave per destination row. lane = (r = lane>>4: edge slot in
// quad, c = lane&15: 16B chunk of the 256B bf16 row). One uint4 load covers
// 4 edges per wave-instruction. Butterfly-combine the 4 edge slots at row end.
template <bool OUT_BF16>
__global__ __launch_bounds__(256) void gather_quad(
    const uint4* __restrict__ feat, const int2* __restrict__ range,
    const int2* __restrict__ payl, void* __restrict__ out, int n_dst) {
  int wid = blockIdx.x * (blockDim.x >> 6) + (threadIdx.x >> 6);
  int lane = threadIdx.x & 63;
  if (wid >= n_dst) return;
  const int r = lane >> 4;
  const int c = lane & 15;
  float a0 = 0.f, a1 = 0.f, a2 = 0.f, a3 = 0.f;
  float a4 = 0.f, a5 = 0.f, a6 = 0.f, a7 = 0.f;
  for (int x = 0; x < NXCD; ++x) {
    const int2 rg = range[(size_t)wid * NXCD + x];
    for (int j = rg.x; j < rg.y; j += 4) {
      int jj = j + r;
      int2 p = make_int2(0, 0);
      if (jj < rg.y) p = payl[jj];
      float w = __int_as_float(p.y);
      uint4 u = feat[(size_t)p.x * 16 + c];
      a0 += __uint_as_float(u.x << 16) * w;
      a1 += __uint_as_float(u.x & 0xffff0000u) * w;
      a2 += __uint_as_float(u.y << 16) * w;
      a3 += __uint_as_float(u.y & 0xffff0000u) * w;
      a4 += __uint_as_float(u.z << 16) * w;
      a5 += __uint_as_float(u.z & 0xffff0000u) * w;
      a6 += __uint_as_float(u.w << 16) * w;
      a7 += __uint_as_float(u.w & 0xffff0000u) * w;
    }
  }
  // Combine the 4 edge slots (lanes c, c+16, c+32, c+48 hold same columns).
  a0 += __shfl_xor(a0, 16); a0 += __shfl_xor(a0, 32);
  a1 += __shfl_xor(a1, 16); a1 += __shfl_xor(a1, 32);
  a2 += __shfl_xor(a2, 16); a2 += __shfl_xor(a2, 32);
  a3 += __shfl_xor(a3, 16); a3 += __shfl_xor(a3, 32);
  a4 += __shfl_xor(a4, 16); a4 += __shfl_xor(a4, 32);
  a5 += __shfl_xor(a5, 16); a5 += __shfl_xor(a5, 32);
  a6 += __shfl_xor(a6, 16); a6 += __shfl_xor(a6, 32);
  a7 += __shfl_xor(a7, 16); a7 += __shfl_xor(a7, 32);
  if (OUT_BF16) {
    if (r == 0) {
      uint4 o = make_uint4(pack_bf16(a0, a1), pack_bf16(a2, a3),
                           pack_bf16(a4, a5), pack_bf16(a6, a7));
      ((uint4*)out)[(size_t)wid * 16 + c] = o;
    }
  } else {
    if (r < 2) {
      float4 o = (r == 0) ? make_float4(a0, a1, a2, a3)
                          : make_float4(a4, a5, a6, a7);
      ((float4*)out)[(size_t)wid * 32 + c * 2 + r] = o;
    }
  }
}

// ------------------------------------------------- fallback (round-1 path)
#define COLG 32
__global__ __launch_bounds__(256) void prop_atomic(
    const float* __restrict__ x, const int* __restrict__ src,
    const int* __restrict__ dst, const float* __restrict__ ew,
    float* __restrict__ out, int E) {
  long long idx = (long long)blockIdx.x * blockDim.x + threadIdx.x;
  long long total = (long long)E * COLG;
  if (idx >= total) return;
  int e = (int)(idx >> 5);
  int cg = (int)(idx & 31);
  int s = src[e];
  int d = dst[e];
  float w = ew[e];
  const float4 v = *reinterpret_cast<const float4*>(x + (size_t)s * DIMS + cg * 4);
  float* o = out + (size_t)d * DIMS + cg * 4;
  atomicAdd(o + 0, v.x * w);
  atomicAdd(o + 1, v.y * w);
  atomicAdd(o + 2, v.z * w);
  atomicAdd(o + 3, v.w * w);
}

// --------------------------------------------------------------- launcher

static inline size_t align_up(size_t v, size_t a) { return (v + a - 1) / a * a; }

extern "C" void kernel_launch(void* const* d_in, const int* in_sizes, int n_in,
                              void* d_out, int out_size, void* d_ws, size_t ws_size,
                              hipStream_t stream) {
  const float* x    = (const float*)d_in[0];
  const int*   src0 = (const int*)d_in[1];
  const int*   dst0 = (const int*)d_in[2];
  const float* ew0  = (const float*)d_in[3];
  const int*   src1 = (const int*)d_in[4];
  const int*   dst1 = (const int*)d_in[5];
  const float* ew1  = (const float*)d_in[6];

  const int N_SRC0 = in_sizes[0] / DIMS;  // 100000
  const int E0 = in_sizes[1];             // 1600000
  const int E1 = in_sizes[4];             // 800000
  const int N_DST0 = 50000;
  const int N_DST1 = 25000;

  float* out = (float*)d_out;

  // --- workspace layout ---
  char* ws = (char*)d_ws;
  size_t off = 0;
  unsigned* xb  = (unsigned*)(ws + off); off = align_up(off + (size_t)N_SRC0 * 64 * 4, 16);
  unsigned* hb  = (unsigned*)(ws + off); off = align_up(off + (size_t)N_DST0 * 64 * 4, 16);
  int* counts   = (int*)(ws + off);      off = align_up(off + (size_t)NXCD * (N_DST0 + N_DST1) * 4, 16);
  int* cursor   = (int*)(ws + off);      off = align_up(off + (size_t)NXCD * (N_DST0 + N_DST1) * 4, 16);
  int* totals   = (int*)(ws + off);      off = align_up(off + (size_t)2 * NXCD * 4, 16);
  int2* range0  = (int2*)(ws + off);     off = align_up(off + (size_t)N_DST0 * NXCD * 8, 64);
  int2* range1  = (int2*)(ws + off);     off = align_up(off + (size_t)N_DST1 * NXCD * 8, 64);
  int2* payl0   = (int2*)(ws + off);     off = align_up(off + (size_t)E0 * 8, 16);
  int2* payl1   = (int2*)(ws + off);     off = align_up(off + (size_t)E1 * 8, 16);
  const size_t needed = off;

  if (ws_size < needed) {
    // Fallback: round-1 atomic path (f32 h at ws front).
    float* h = (float*)d_ws;
    hipMemsetAsync(h, 0, (size_t)N_DST0 * DIMS * 4, stream);
    hipMemsetAsync(out, 0, (size_t)N_DST1 * DIMS * 4, stream);
    long long t0 = (long long)E0 * COLG;
    prop_atomic<<<(int)((t0 + 255) / 256), 256, 0, stream>>>(x, src0, dst0, ew0, h, E0);
    long long t1 = (long long)E1 * COLG;
    prop_atomic<<<(int)((t1 + 255) / 256), 256, 0, stream>>>(h, src1, dst1, ew1, out, E1);
    return;
  }

  const long long n2 = (long long)N_SRC0 * 64;   // bf16x2 words in x

  // 1. zero counts (both stages)
  hipMemsetAsync(counts, 0, (size_t)NXCD * (N_DST0 + N_DST1) * 4, stream);

  // 2. fused degree-count (both stages) + f32->bf16 conversion
  {
    int cntBlocks = (E0 + E1 + 255) / 256;
    int cvtBlocks = (int)((n2 + 255) / 256);
    count_cvt<<<cntBlocks + cvtBlocks, 256, 0, stream>>>(
        dst0, dst1, counts, x, xb, E0, E1, N_DST0, N_DST1, cntBlocks, n2);
  }

  // 3. per-segment scans (16 blocks: 8 per stage)
  scan_seg16<<<2 * NXCD, 1024, 0, stream>>>(counts, cursor, totals, N_DST0, N_DST1);

  // 4. materialize per-row segment ranges (must precede scatter: reads cursor)
  {
    int tot = NXCD * (N_DST0 + N_DST1);
    mkranges<<<(tot + 255) / 256, 256, 0, stream>>>(counts, cursor, totals,
                                                    range0, range1, N_DST0, N_DST1);
  }

  // 5. fused scatter (both stages) into XCD-private payload regions
  scatter_both<<<(E0 + E1 + 255) / 256, 256, 0, stream>>>(
      src0, dst0, ew0, src1, dst1, ew1, cursor, totals, payl0, payl1,
      E0, E1, N_DST0, N_DST1);

  // 6. stage-1 gather: hb[dst0] += xb[src0] * ew0  (bf16 out)
  gather_quad<true><<<(N_DST0 + 3) / 4, 256, 0, stream>>>(
      (const uint4*)xb, range0, payl0, (void*)hb, N_DST0);

  // 7. stage-2 gather: out[dst1] += hb[src1] * ew1  (f32 out)
  gather_quad<false><<<(N_DST1 + 3) / 4, 256, 0, stream>>>(
      (const uint4*)hb, range1, payl1, (void*)out, N_DST1);
}

// Round 7
// 273.847 us; speedup vs baseline: 14.6844x; 1.6938x over previous
//
#include <hip/hip_runtime.h>

// LightGCN forward: two gather-scale-scatter-sum propagations.
// Round 7: bucket-CSR. Round-6 profile: per-dst scatter wrote 121 MB for a
// 19.2 MB payload (one line eviction per random 8B append — appends to a
// dst's tail are spread across the whole edge stream, so lines never merge
// in L2), and exact per-dst CSR needed 2.4M global atomics + scan.
// Here: coarse 64-dst buckets (LDS histogram -> scan -> chunked partition
// with contiguous per-(chunk,bucket) runs => merged writes), then one
// workgroup per bucket counting-sorts its ~2048 edges in LDS and runs the
// round-6 quad-register-gather per dst. bf16 features (round 5) kept.
//
// Sizes: x [100000,128] f32; E0=1.6M edges -> 50000 dsts; E1=0.8M -> 25000.

#define DIMS 128
#define BK   64      // dsts per bucket
#define BKSH 6
#define CAP  4096    // LDS-staged edges per bucket (mean 2048, +45 sigma)
#define CH   8192    // edges per partition chunk

__device__ __forceinline__ unsigned bf16_1(float a) {
  unsigned u = __float_as_uint(a);
  return (u + 0x7fffu + ((u >> 16) & 1u)) >> 16;   // RNE
}
__device__ __forceinline__ unsigned pack_bf16(float a, float b) {
  return bf16_1(a) | (bf16_1(b) << 16);
}

// ---------------------------------------- K1: per-chunk bucket histogram + cvt
// Blocks [0, NW0+NW1): histogram chunks (stage0 then stage1).
// Blocks beyond: f32 -> bf16 conversion of x (uint4 per thread = 8 cols).
__global__ __launch_bounds__(256) void hist_cvt(
    const int* __restrict__ dst0, const int* __restrict__ dst1,
    const float* __restrict__ xf, uint4* __restrict__ xbf4,
    int* __restrict__ wgcnt0, int* __restrict__ wgcnt1,
    int E0, int E1, int NB0, int NB1, int NW0, int NW1, long long n8) {
  int b = blockIdx.x;
  if (b < NW0 + NW1) {
    __shared__ int hist[1024];
    const int s1 = (b >= NW0);
    const int w  = s1 ? b - NW0 : b;
    const int E  = s1 ? E1 : E0;
    const int NB = s1 ? NB1 : NB0;
    const int* dst = s1 ? dst1 : dst0;
    int* wgcnt = s1 ? wgcnt1 : wgcnt0;
    for (int i = threadIdx.x; i < NB; i += 256) hist[i] = 0;
    __syncthreads();
    const int beg = w * CH, end = min(beg + CH, E);
    for (int e = beg + threadIdx.x; e < end; e += 256)
      atomicAdd(&hist[dst[e] >> BKSH], 1);
    __syncthreads();
    for (int i = threadIdx.x; i < NB; i += 256)
      wgcnt[w * NB + i] = hist[i];          // [chunk][bucket] -> coalesced
  } else {
    long long t = (long long)(b - NW0 - NW1) * 256 + threadIdx.x;
    if (t < n8) {
      const float4* xf4 = (const float4*)xf;
      float4 v0 = xf4[t * 2], v1 = xf4[t * 2 + 1];
      xbf4[t] = make_uint4(pack_bf16(v0.x, v0.y), pack_bf16(v0.z, v0.w),
                           pack_bf16(v1.x, v1.y), pack_bf16(v1.z, v1.w));
    }
  }
}

// ------------------------- K2: scans. Block 0: stage0, block 1: stage1.
// Thread t owns bucket t: serial exclusive prefix over chunks (coalesced
// across threads), LDS scan over bucket totals, add base back, emit ranges.
__global__ __launch_bounds__(1024) void scan2(
    int* __restrict__ wgcnt0, int* __restrict__ wgcnt1,
    int2* __restrict__ rg0, int2* __restrict__ rg1,
    int NB0, int NB1, int NW0, int NW1) {
  __shared__ int part[1024];
  const int s1 = blockIdx.x;
  int* wgcnt = s1 ? wgcnt1 : wgcnt0;
  int2* rg   = s1 ? rg1 : rg0;
  const int NB = s1 ? NB1 : NB0;
  const int NW = s1 ? NW1 : NW0;
  const int t = threadIdx.x;
  int tot = 0;
  if (t < NB) {
    for (int w = 0; w < NW; ++w) {
      int c = wgcnt[w * NB + t];
      wgcnt[w * NB + t] = tot;
      tot += c;
    }
  }
  part[t] = tot;
  __syncthreads();
  for (int off = 1; off < 1024; off <<= 1) {
    int v = (t >= off) ? part[t - off] : 0;
    __syncthreads();
    part[t] += v;
    __syncthreads();
  }
  int base = (t == 0) ? 0 : part[t - 1];
  if (t < NB) {
    for (int w = 0; w < NW; ++w) wgcnt[w * NB + t] += base;
    rg[t] = make_int2(base, base + tot);
  }
}

// -------------------------------- K3: chunked partition into bucket regions.
// Payload: x = src id; y = (bf16(weight) << 16) | (dst & 63).
__global__ __launch_bounds__(256) void partition_k(
    const int* __restrict__ src0, const int* __restrict__ dst0,
    const float* __restrict__ ew0, const int* __restrict__ src1,
    const int* __restrict__ dst1, const float* __restrict__ ew1,
    const int* __restrict__ wgcnt0, const int* __restrict__ wgcnt1,
    int2* __restrict__ payl0, int2* __restrict__ payl1,
    int E0, int E1, int NB0, int NB1, int NW0, int NW1) {
  __shared__ int cur[1024];
  int b = blockIdx.x;
  const int s1 = (b >= NW0);
  const int w  = s1 ? b - NW0 : b;
  const int E  = s1 ? E1 : E0;
  const int NB = s1 ? NB1 : NB0;
  const int* src = s1 ? src1 : src0;
  const int* dst = s1 ? dst1 : dst0;
  const float* ew = s1 ? ew1 : ew0;
  const int* wgcnt = s1 ? wgcnt1 : wgcnt0;
  int2* payl = s1 ? payl1 : payl0;
  for (int i = threadIdx.x; i < NB; i += 256) cur[i] = wgcnt[w * NB + i];
  __syncthreads();
  const int beg = w * CH, end = min(beg + CH, E);
  for (int e = beg + threadIdx.x; e < end; e += 256) {
    int d = dst[e];
    int pos = atomicAdd(&cur[d >> BKSH], 1);
    payl[pos] = make_int2(src[e],
                          (int)((bf16_1(ew[e]) << 16) | (unsigned)(d & (BK - 1))));
  }
}

// ------------------------------- K4/K5: bucket gather (one workgroup/bucket).
// Counting-sort bucket edges by dst-low bits into LDS, then per-dst
// quad-register-gather: lane=(r=edge slot 0..3, c=16B chunk 0..15), uint4
// bf16 row loads, shfl_xor combine, one vector store per dst row.
template <bool OUT_BF16>
__global__ __launch_bounds__(256) void gather_bkt(
    const uint4* __restrict__ feat, const int2* __restrict__ rg,
    const int2* __restrict__ payl, void* __restrict__ outp, int n_dst) {
  __shared__ int2 lp[CAP];
  __shared__ int cnt[BK], base[BK], cnt2[BK];
  const int b = blockIdx.x;
  const int tid = threadIdx.x;
  const int2 r = rg[b];
  const int n = r.y - r.x;
  const int nin = min(n, CAP);
  if (tid < BK) { cnt[tid] = 0; cnt2[tid] = 0; }
  __syncthreads();
  for (int j = tid; j < nin; j += 256)
    atomicAdd(&cnt[payl[r.x + j].y & (BK - 1)], 1);
  __syncthreads();
  if (tid < 64) {                         // exclusive scan of cnt[64], wave 0
    int v = cnt[tid];
    int s = v;
    for (int off = 1; off < 64; off <<= 1) {
      int u = __shfl_up(s, off);
      if (tid >= off) s += u;
    }
    base[tid] = s - v;
  }
  __syncthreads();
  for (int j = tid; j < nin; j += 256) {  // place
    int2 p = payl[r.x + j];
    int dl = p.y & (BK - 1);
    int pos = base[dl] + atomicAdd(&cnt2[dl], 1);
    lp[pos] = p;
  }
  __syncthreads();
  const int wave = tid >> 6;
  const int lane = tid & 63;
  const int rr = lane >> 4;
  const int c  = lane & 15;
  for (int dl = wave; dl < BK; dl += 4) {
    const int row = b * BK + dl;
    if (row >= n_dst) break;              // only last bucket; monotone in dl
    const int bg = base[dl];
    const int en = bg + cnt[dl];
    float a0 = 0.f, a1 = 0.f, a2 = 0.f, a3 = 0.f;
    float a4 = 0.f, a5 = 0.f, a6 = 0.f, a7 = 0.f;
    for (int j = bg; j < en; j += 4) {
      int jj = j + rr;
      int2 p = (jj < en) ? lp[jj] : make_int2(0, 0);
      float wgt = __uint_as_float((unsigned)p.y & 0xffff0000u);
      uint4 u = feat[(size_t)p.x * 16 + c];
      a0 += __uint_as_float(u.x << 16) * wgt;
      a1 += __uint_as_float(u.x & 0xffff0000u) * wgt;
      a2 += __uint_as_float(u.y << 16) * wgt;
      a3 += __uint_as_float(u.y & 0xffff0000u) * wgt;
      a4 += __uint_as_float(u.z << 16) * wgt;
      a5 += __uint_as_float(u.z & 0xffff0000u) * wgt;
      a6 += __uint_as_float(u.w << 16) * wgt;
      a7 += __uint_as_float(u.w & 0xffff0000u) * wgt;
    }
    if (n > CAP) {                        // overflow tail (never for this input)
      for (int j = CAP; j < n; j += 4) {
        int jj = j + rr;
        int2 p = (jj < n) ? payl[r.x + jj] : make_int2(0, 0);
        bool mine = (jj < n) && ((p.y & (BK - 1)) == dl);
        float wgt = mine ? __uint_as_float((unsigned)p.y & 0xffff0000u) : 0.f;
        uint4 u = feat[(size_t)p.x * 16 + c];
        a0 += __uint_as_float(u.x << 16) * wgt;
        a1 += __uint_as_float(u.x & 0xffff0000u) * wgt;
        a2 += __uint_as_float(u.y << 16) * wgt;
        a3 += __uint_as_float(u.y & 0xffff0000u) * wgt;
        a4 += __uint_as_float(u.z << 16) * wgt;
        a5 += __uint_as_float(u.z & 0xffff0000u) * wgt;
        a6 += __uint_as_float(u.w << 16) * wgt;
        a7 += __uint_as_float(u.w & 0xffff0000u) * wgt;
      }
    }
    a0 += __shfl_xor(a0, 16); a0 += __shfl_xor(a0, 32);
    a1 += __shfl_xor(a1, 16); a1 += __shfl_xor(a1, 32);
    a2 += __shfl_xor(a2, 16); a2 += __shfl_xor(a2, 32);
    a3 += __shfl_xor(a3, 16); a3 += __shfl_xor(a3, 32);
    a4 += __shfl_xor(a4, 16); a4 += __shfl_xor(a4, 32);
    a5 += __shfl_xor(a5, 16); a5 += __shfl_xor(a5, 32);
    a6 += __shfl_xor(a6, 16); a6 += __shfl_xor(a6, 32);
    a7 += __shfl_xor(a7, 16); a7 += __shfl_xor(a7, 32);
    if (OUT_BF16) {
      if (rr == 0) {
        ((uint4*)outp)[(size_t)row * 16 + c] =
            make_uint4(pack_bf16(a0, a1), pack_bf16(a2, a3),
                       pack_bf16(a4, a5), pack_bf16(a6, a7));
      }
    } else {
      if (rr < 2) {
        ((float4*)outp)[(size_t)row * 32 + c * 2 + rr] =
            (rr == 0) ? make_float4(a0, a1, a2, a3)
                      : make_float4(a4, a5, a6, a7);
      }
    }
  }
}

// ------------------------------------------------- fallback (round-1 path)
#define COLG 32
__global__ __launch_bounds__(256) void prop_atomic(
    const float* __restrict__ x, const int* __restrict__ src,
    const int* __restrict__ dst, const float* __restrict__ ew,
    float* __restrict__ out, int E) {
  long long idx = (long long)blockIdx.x * blockDim.x + threadIdx.x;
  long long total = (long long)E * COLG;
  if (idx >= total) return;
  int e = (int)(idx >> 5);
  int cg = (int)(idx & 31);
  int s = src[e];
  int d = dst[e];
  float w = ew[e];
  const float4 v = *reinterpret_cast<const float4*>(x + (size_t)s * DIMS + cg * 4);
  float* o = out + (size_t)d * DIMS + cg * 4;
  atomicAdd(o + 0, v.x * w);
  atomicAdd(o + 1, v.y * w);
  atomicAdd(o + 2, v.z * w);
  atomicAdd(o + 3, v.w * w);
}

// --------------------------------------------------------------- launcher

static inline size_t align_up(size_t v, size_t a) { return (v + a - 1) / a * a; }

extern "C" void kernel_launch(void* const* d_in, const int* in_sizes, int n_in,
                              void* d_out, int out_size, void* d_ws, size_t ws_size,
                              hipStream_t stream) {
  const float* x    = (const float*)d_in[0];
  const int*   src0 = (const int*)d_in[1];
  const int*   dst0 = (const int*)d_in[2];
  const float* ew0  = (const float*)d_in[3];
  const int*   src1 = (const int*)d_in[4];
  const int*   dst1 = (const int*)d_in[5];
  const float* ew1  = (const float*)d_in[6];

  const int N_SRC0 = in_sizes[0] / DIMS;  // 100000
  const int E0 = in_sizes[1];             // 1600000
  const int E1 = in_sizes[4];             // 800000
  const int N_DST0 = 50000;
  const int N_DST1 = 25000;

  const int NB0 = (N_DST0 + BK - 1) / BK;   // 782
  const int NB1 = (N_DST1 + BK - 1) / BK;   // 391
  const int NW0 = (E0 + CH - 1) / CH;       // 196
  const int NW1 = (E1 + CH - 1) / CH;       // 98

  float* out = (float*)d_out;

  // --- workspace layout ---
  char* ws = (char*)d_ws;
  size_t off = 0;
  uint4* xb    = (uint4*)(ws + off); off = align_up(off + (size_t)N_SRC0 * 64 * 4, 16);
  uint4* hb    = (uint4*)(ws + off); off = align_up(off + (size_t)N_DST0 * 64 * 4, 16);
  int* wgcnt0  = (int*)(ws + off);   off = align_up(off + (size_t)NW0 * NB0 * 4, 16);
  int* wgcnt1  = (int*)(ws + off);   off = align_up(off + (size_t)NW1 * NB1 * 4, 16);
  int2* rg0    = (int2*)(ws + off);  off = align_up(off + (size_t)NB0 * 8, 16);
  int2* rg1    = (int2*)(ws + off);  off = align_up(off + (size_t)NB1 * 8, 16);
  int2* payl0  = (int2*)(ws + off);  off = align_up(off + (size_t)E0 * 8, 16);
  int2* payl1  = (int2*)(ws + off);  off = align_up(off + (size_t)E1 * 8, 16);
  const size_t needed = off;

  if (ws_size < needed) {
    float* h = (float*)d_ws;
    hipMemsetAsync(h, 0, (size_t)N_DST0 * DIMS * 4, stream);
    hipMemsetAsync(out, 0, (size_t)N_DST1 * DIMS * 4, stream);
    long long t0 = (long long)E0 * COLG;
    prop_atomic<<<(int)((t0 + 255) / 256), 256, 0, stream>>>(x, src0, dst0, ew0, h, E0);
    long long t1 = (long long)E1 * COLG;
    prop_atomic<<<(int)((t1 + 255) / 256), 256, 0, stream>>>(h, src1, dst1, ew1, out, E1);
    return;
  }

  const long long n8 = (long long)N_SRC0 * 16;   // uint4 words in xb
  const int cvtBlocks = (int)((n8 + 255) / 256);

  // K1: bucket histograms (both stages) + f32->bf16 conversion
  hist_cvt<<<NW0 + NW1 + cvtBlocks, 256, 0, stream>>>(
      dst0, dst1, x, xb, wgcnt0, wgcnt1, E0, E1, NB0, NB1, NW0, NW1, n8);

  // K2: per-bucket chunk-prefix + bucket-base scan (both stages)
  scan2<<<2, 1024, 0, stream>>>(wgcnt0, wgcnt1, rg0, rg1, NB0, NB1, NW0, NW1);

  // K3: partition edges into bucket regions (both stages)
  partition_k<<<NW0 + NW1, 256, 0, stream>>>(
      src0, dst0, ew0, src1, dst1, ew1, wgcnt0, wgcnt1, payl0, payl1,
      E0, E1, NB0, NB1, NW0, NW1);

  // K4: stage-1 gather: hb[dst0] += xb[src0] * ew0  (bf16 out)
  gather_bkt<true><<<NB0, 256, 0, stream>>>(xb, rg0, payl0, (void*)hb, N_DST0);

  // K5: stage-2 gather: out[dst1] += hb[src1] * ew1  (f32 out)
  gather_bkt<false><<<NB1, 256, 0, stream>>>(hb, rg1, payl1, (void*)out, N_DST1);
}

// Round 8
// 206.846 us; speedup vs baseline: 19.4410x; 1.3239x over previous
//
#include <hip/hip_runtime.h>

// LightGCN forward: two gather-scale-scatter-sum propagations.
// Round 8: parallel CSR scans. Round-7 profile: scan2 (2 blocks, serial
// 196-chunk walk per thread) was the top dispatch at 80 us / 0.2% occupancy.
// Replaced by scan_cols (one block per bucket, one chunk per thread,
// block-wide Hillis-Steele) + scan_tot (bucket-total scan -> ranges).
// Partition adds the bucket base at LDS-init. Bucket-CSR (r7), quad-gather
// (r6), bf16 features (r5) kept.
//
// Sizes: x [100000,128] f32; E0=1.6M edges -> 50000 dsts; E1=0.8M -> 25000.

#define DIMS 128
#define BK   64      // dsts per bucket
#define BKSH 6
#define CAP  4096    // LDS-staged edges per bucket (mean 2048, +45 sigma)
#define CH   8192    // edges per partition chunk

__device__ __forceinline__ unsigned bf16_1(float a) {
  unsigned u = __float_as_uint(a);
  return (u + 0x7fffu + ((u >> 16) & 1u)) >> 16;   // RNE
}
__device__ __forceinline__ unsigned pack_bf16(float a, float b) {
  return bf16_1(a) | (bf16_1(b) << 16);
}

// ---------------------------------------- K1: per-chunk bucket histogram + cvt
// Blocks [0, NW0+NW1): histogram chunks (stage0 then stage1).
// Blocks beyond: f32 -> bf16 conversion of x (uint4 per thread = 8 cols).
__global__ __launch_bounds__(256) void hist_cvt(
    const int* __restrict__ dst0, const int* __restrict__ dst1,
    const float* __restrict__ xf, uint4* __restrict__ xbf4,
    int* __restrict__ wgcnt0, int* __restrict__ wgcnt1,
    int E0, int E1, int NB0, int NB1, int NW0, int NW1, long long n8) {
  int b = blockIdx.x;
  if (b < NW0 + NW1) {
    __shared__ int hist[1024];
    const int s1 = (b >= NW0);
    const int w  = s1 ? b - NW0 : b;
    const int E  = s1 ? E1 : E0;
    const int NB = s1 ? NB1 : NB0;
    const int* dst = s1 ? dst1 : dst0;
    int* wgcnt = s1 ? wgcnt1 : wgcnt0;
    for (int i = threadIdx.x; i < NB; i += 256) hist[i] = 0;
    __syncthreads();
    const int beg = w * CH, end = min(beg + CH, E);
    for (int e = beg + threadIdx.x; e < end; e += 256)
      atomicAdd(&hist[dst[e] >> BKSH], 1);
    __syncthreads();
    for (int i = threadIdx.x; i < NB; i += 256)
      wgcnt[w * NB + i] = hist[i];          // [chunk][bucket] -> coalesced
  } else {
    long long t = (long long)(b - NW0 - NW1) * 256 + threadIdx.x;
    if (t < n8) {
      const float4* xf4 = (const float4*)xf;
      float4 v0 = xf4[t * 2], v1 = xf4[t * 2 + 1];
      xbf4[t] = make_uint4(pack_bf16(v0.x, v0.y), pack_bf16(v0.z, v0.w),
                           pack_bf16(v1.x, v1.y), pack_bf16(v1.z, v1.w));
    }
  }
}

// ---------------- K2a: per-bucket chunk-prefix scan. One block per bucket.
// Thread w holds chunk w's count for this bucket (NW <= 256): block scan,
// write back exclusive prefix, emit bucket total.
__global__ __launch_bounds__(256) void scan_cols(
    int* __restrict__ wgcnt0, int* __restrict__ wgcnt1,
    int* __restrict__ tot0, int* __restrict__ tot1,
    int NB0, int NB1, int NW0, int NW1) {
  __shared__ int part[256];
  int b = blockIdx.x;
  const int s1 = (b >= NB0);
  const int i = s1 ? b - NB0 : b;
  int* wgcnt = s1 ? wgcnt1 : wgcnt0;
  int* tot   = s1 ? tot1 : tot0;
  const int NB = s1 ? NB1 : NB0;
  const int NW = s1 ? NW1 : NW0;
  const int t = threadIdx.x;
  int v = (t < NW) ? wgcnt[t * NB + i] : 0;
  part[t] = v;
  __syncthreads();
  for (int off = 1; off < 256; off <<= 1) {
    int u = (t >= off) ? part[t - off] : 0;
    __syncthreads();
    part[t] += u;
    __syncthreads();
  }
  if (t < NW) wgcnt[t * NB + i] = part[t] - v;   // exclusive (bucket-local)
  if (t == 255) tot[i] = part[255];
}

// ---------------- K2b: bucket-total scan -> global ranges. 2 blocks.
__global__ __launch_bounds__(1024) void scan_tot(
    const int* __restrict__ tot0, const int* __restrict__ tot1,
    int2* __restrict__ rg0, int2* __restrict__ rg1, int NB0, int NB1) {
  __shared__ int part[1024];
  const int s1 = blockIdx.x;
  const int* tot = s1 ? tot1 : tot0;
  int2* rg = s1 ? rg1 : rg0;
  const int NB = s1 ? NB1 : NB0;
  const int t = threadIdx.x;
  int v = (t < NB) ? tot[t] : 0;
  part[t] = v;
  __syncthreads();
  for (int off = 1; off < 1024; off <<= 1) {
    int u = (t >= off) ? part[t - off] : 0;
    __syncthreads();
    part[t] += u;
    __syncthreads();
  }
  if (t < NB) rg[t] = make_int2(part[t] - v, part[t]);
}

// -------------------------------- K3: chunked partition into bucket regions.
// Payload: x = src id; y = (bf16(weight) << 16) | (dst & 63).
__global__ __launch_bounds__(256) void partition_k(
    const int* __restrict__ src0, const int* __restrict__ dst0,
    const float* __restrict__ ew0, const int* __restrict__ src1,
    const int* __restrict__ dst1, const float* __restrict__ ew1,
    const int* __restrict__ wgcnt0, const int* __restrict__ wgcnt1,
    const int2* __restrict__ rg0, const int2* __restrict__ rg1,
    int2* __restrict__ payl0, int2* __restrict__ payl1,
    int E0, int E1, int NB0, int NB1, int NW0, int NW1) {
  __shared__ int cur[1024];
  int b = blockIdx.x;
  const int s1 = (b >= NW0);
  const int w  = s1 ? b - NW0 : b;
  const int E  = s1 ? E1 : E0;
  const int NB = s1 ? NB1 : NB0;
  const int* src = s1 ? src1 : src0;
  const int* dst = s1 ? dst1 : dst0;
  const float* ew = s1 ? ew1 : ew0;
  const int* wgcnt = s1 ? wgcnt1 : wgcnt0;
  const int2* rg = s1 ? rg1 : rg0;
  int2* payl = s1 ? payl1 : payl0;
  for (int i = threadIdx.x; i < NB; i += 256)
    cur[i] = rg[i].x + wgcnt[w * NB + i];
  __syncthreads();
  const int beg = w * CH, end = min(beg + CH, E);
  for (int e = beg + threadIdx.x; e < end; e += 256) {
    int d = dst[e];
    int pos = atomicAdd(&cur[d >> BKSH], 1);
    payl[pos] = make_int2(src[e],
                          (int)((bf16_1(ew[e]) << 16) | (unsigned)(d & (BK - 1))));
  }
}

// ------------------------------- K4/K5: bucket gather (one workgroup/bucket).
// Counting-sort bucket edges by dst-low bits into LDS, then per-dst
// quad-register-gather: lane=(r=edge slot 0..3, c=16B chunk 0..15), uint4
// bf16 row loads, shfl_xor combine, one vector store per dst row.
template <bool OUT_BF16>
__global__ __launch_bounds__(256) void gather_bkt(
    const uint4* __restrict__ feat, const int2* __restrict__ rg,
    const int2* __restrict__ payl, void* __restrict__ outp, int n_dst) {
  __shared__ int2 lp[CAP];
  __shared__ int cnt[BK], base[BK], cnt2[BK];
  const int b = blockIdx.x;
  const int tid = threadIdx.x;
  const int2 r = rg[b];
  const int n = r.y - r.x;
  const int nin = min(n, CAP);
  if (tid < BK) { cnt[tid] = 0; cnt2[tid] = 0; }
  __syncthreads();
  for (int j = tid; j < nin; j += 256)
    atomicAdd(&cnt[payl[r.x + j].y & (BK - 1)], 1);
  __syncthreads();
  if (tid < 64) {                         // exclusive scan of cnt[64], wave 0
    int v = cnt[tid];
    int s = v;
    for (int off = 1; off < 64; off <<= 1) {
      int u = __shfl_up(s, off);
      if (tid >= off) s += u;
    }
    base[tid] = s - v;
  }
  __syncthreads();
  for (int j = tid; j < nin; j += 256) {  // place
    int2 p = payl[r.x + j];
    int dl = p.y & (BK - 1);
    int pos = base[dl] + atomicAdd(&cnt2[dl], 1);
    lp[pos] = p;
  }
  __syncthreads();
  const int wave = tid >> 6;
  const int lane = tid & 63;
  const int rr = lane >> 4;
  const int c  = lane & 15;
  for (int dl = wave; dl < BK; dl += 4) {
    const int row = b * BK + dl;
    if (row >= n_dst) break;              // only last bucket; monotone in dl
    const int bg = base[dl];
    const int en = bg + cnt[dl];
    float a0 = 0.f, a1 = 0.f, a2 = 0.f, a3 = 0.f;
    float a4 = 0.f, a5 = 0.f, a6 = 0.f, a7 = 0.f;
    for (int j = bg; j < en; j += 4) {
      int jj = j + rr;
      int2 p = (jj < en) ? lp[jj] : make_int2(0, 0);
      float wgt = __uint_as_float((unsigned)p.y & 0xffff0000u);
      uint4 u = feat[(size_t)p.x * 16 + c];
      a0 += __uint_as_float(u.x << 16) * wgt;
      a1 += __uint_as_float(u.x & 0xffff0000u) * wgt;
      a2 += __uint_as_float(u.y << 16) * wgt;
      a3 += __uint_as_float(u.y & 0xffff0000u) * wgt;
      a4 += __uint_as_float(u.z << 16) * wgt;
      a5 += __uint_as_float(u.z & 0xffff0000u) * wgt;
      a6 += __uint_as_float(u.w << 16) * wgt;
      a7 += __uint_as_float(u.w & 0xffff0000u) * wgt;
    }
    if (n > CAP) {                        // overflow tail (never for this input)
      for (int j = CAP; j < n; j += 4) {
        int jj = j + rr;
        int2 p = (jj < n) ? payl[r.x + jj] : make_int2(0, 0);
        bool mine = (jj < n) && ((p.y & (BK - 1)) == dl);
        float wgt = mine ? __uint_as_float((unsigned)p.y & 0xffff0000u) : 0.f;
        uint4 u = feat[(size_t)p.x * 16 + c];
        a0 += __uint_as_float(u.x << 16) * wgt;
        a1 += __uint_as_float(u.x & 0xffff0000u) * wgt;
        a2 += __uint_as_float(u.y << 16) * wgt;
        a3 += __uint_as_float(u.y & 0xffff0000u) * wgt;
        a4 += __uint_as_float(u.z << 16) * wgt;
        a5 += __uint_as_float(u.z & 0xffff0000u) * wgt;
        a6 += __uint_as_float(u.w << 16) * wgt;
        a7 += __uint_as_float(u.w & 0xffff0000u) * wgt;
      }
    }
    a0 += __shfl_xor(a0, 16); a0 += __shfl_xor(a0, 32);
    a1 += __shfl_xor(a1, 16); a1 += __shfl_xor(a1, 32);
    a2 += __shfl_xor(a2, 16); a2 += __shfl_xor(a2, 32);
    a3 += __shfl_xor(a3, 16); a3 += __shfl_xor(a3, 32);
    a4 += __shfl_xor(a4, 16); a4 += __shfl_xor(a4, 32);
    a5 += __shfl_xor(a5, 16); a5 += __shfl_xor(a5, 32);
    a6 += __shfl_xor(a6, 16); a6 += __shfl_xor(a6, 32);
    a7 += __shfl_xor(a7, 16); a7 += __shfl_xor(a7, 32);
    if (OUT_BF16) {
      if (rr == 0) {
        ((uint4*)outp)[(size_t)row * 16 + c] =
            make_uint4(pack_bf16(a0, a1), pack_bf16(a2, a3),
                       pack_bf16(a4, a5), pack_bf16(a6, a7));
      }
    } else {
      if (rr < 2) {
        ((float4*)outp)[(size_t)row * 32 + c * 2 + rr] =
            (rr == 0) ? make_float4(a0, a1, a2, a3)
                      : make_float4(a4, a5, a6, a7);
      }
    }
  }
}

// ------------------------------------------------- fallback (round-1 path)
#define COLG 32
__global__ __launch_bounds__(256) void prop_atomic(
    const float* __restrict__ x, const int* __restrict__ src,
    const int* __restrict__ dst, const float* __restrict__ ew,
    float* __restrict__ out, int E) {
  long long idx = (long long)blockIdx.x * blockDim.x + threadIdx.x;
  long long total = (long long)E * COLG;
  if (idx >= total) return;
  int e = (int)(idx >> 5);
  int cg = (int)(idx & 31);
  int s = src[e];
  int d = dst[e];
  float w = ew[e];
  const float4 v = *reinterpret_cast<const float4*>(x + (size_t)s * DIMS + cg * 4);
  float* o = out + (size_t)d * DIMS + cg * 4;
  atomicAdd(o + 0, v.x * w);
  atomicAdd(o + 1, v.y * w);
  atomicAdd(o + 2, v.z * w);
  atomicAdd(o + 3, v.w * w);
}

// --------------------------------------------------------------- launcher

static inline size_t align_up(size_t v, size_t a) { return (v + a - 1) / a * a; }

extern "C" void kernel_launch(void* const* d_in, const int* in_sizes, int n_in,
                              void* d_out, int out_size, void* d_ws, size_t ws_size,
                              hipStream_t stream) {
  const float* x    = (const float*)d_in[0];
  const int*   src0 = (const int*)d_in[1];
  const int*   dst0 = (const int*)d_in[2];
  const float* ew0  = (const float*)d_in[3];
  const int*   src1 = (const int*)d_in[4];
  const int*   dst1 = (const int*)d_in[5];
  const float* ew1  = (const float*)d_in[6];

  const int N_SRC0 = in_sizes[0] / DIMS;  // 100000
  const int E0 = in_sizes[1];             // 1600000
  const int E1 = in_sizes[4];             // 800000
  const int N_DST0 = 50000;
  const int N_DST1 = 25000;

  const int NB0 = (N_DST0 + BK - 1) / BK;   // 782
  const int NB1 = (N_DST1 + BK - 1) / BK;   // 391
  const int NW0 = (E0 + CH - 1) / CH;       // 196
  const int NW1 = (E1 + CH - 1) / CH;       // 98

  float* out = (float*)d_out;

  // --- workspace layout ---
  char* ws = (char*)d_ws;
  size_t off = 0;
  uint4* xb    = (uint4*)(ws + off); off = align_up(off + (size_t)N_SRC0 * 64 * 4, 16);
  uint4* hb    = (uint4*)(ws + off); off = align_up(off + (size_t)N_DST0 * 64 * 4, 16);
  int* wgcnt0  = (int*)(ws + off);   off = align_up(off + (size_t)NW0 * NB0 * 4, 16);
  int* wgcnt1  = (int*)(ws + off);   off = align_up(off + (size_t)NW1 * NB1 * 4, 16);
  int* tot0    = (int*)(ws + off);   off = align_up(off + (size_t)NB0 * 4, 16);
  int* tot1    = (int*)(ws + off);   off = align_up(off + (size_t)NB1 * 4, 16);
  int2* rg0    = (int2*)(ws + off);  off = align_up(off + (size_t)NB0 * 8, 16);
  int2* rg1    = (int2*)(ws + off);  off = align_up(off + (size_t)NB1 * 8, 16);
  int2* payl0  = (int2*)(ws + off);  off = align_up(off + (size_t)E0 * 8, 16);
  int2* payl1  = (int2*)(ws + off);  off = align_up(off + (size_t)E1 * 8, 16);
  const size_t needed = off;

  if (ws_size < needed) {
    float* h = (float*)d_ws;
    hipMemsetAsync(h, 0, (size_t)N_DST0 * DIMS * 4, stream);
    hipMemsetAsync(out, 0, (size_t)N_DST1 * DIMS * 4, stream);
    long long t0 = (long long)E0 * COLG;
    prop_atomic<<<(int)((t0 + 255) / 256), 256, 0, stream>>>(x, src0, dst0, ew0, h, E0);
    long long t1 = (long long)E1 * COLG;
    prop_atomic<<<(int)((t1 + 255) / 256), 256, 0, stream>>>(h, src1, dst1, ew1, out, E1);
    return;
  }

  const long long n8 = (long long)N_SRC0 * 16;   // uint4 words in xb
  const int cvtBlocks = (int)((n8 + 255) / 256);

  // K1: bucket histograms (both stages) + f32->bf16 conversion
  hist_cvt<<<NW0 + NW1 + cvtBlocks, 256, 0, stream>>>(
      dst0, dst1, x, xb, wgcnt0, wgcnt1, E0, E1, NB0, NB1, NW0, NW1, n8);

  // K2a: per-bucket chunk-prefix scan (one block per bucket, both stages)
  scan_cols<<<NB0 + NB1, 256, 0, stream>>>(wgcnt0, wgcnt1, tot0, tot1,
                                           NB0, NB1, NW0, NW1);

  // K2b: bucket-total scan -> global ranges (both stages)
  scan_tot<<<2, 1024, 0, stream>>>(tot0, tot1, rg0, rg1, NB0, NB1);

  // K3: partition edges into bucket regions (both stages)
  partition_k<<<NW0 + NW1, 256, 0, stream>>>(
      src0, dst0, ew0, src1, dst1, ew1, wgcnt0, wgcnt1, rg0, rg1,
      payl0, payl1, E0, E1, NB0, NB1, NW0, NW1);

  // K4: stage-1 gather: hb[dst0] += xb[src0] * ew0  (bf16 out)
  gather_bkt<true><<<NB0, 256, 0, stream>>>(xb, rg0, payl0, (void*)hb, N_DST0);

  // K5: stage-2 gather: out[dst1] += hb[src1] * ew1  (f32 out)
  gather_bkt<false><<<NB1, 256, 0, stream>>>(hb, rg1, payl1, (void*)out, N_DST1);
}

// Round 9
// 159.008 us; speedup vs baseline: 25.2899x; 1.3009x over previous
//
#include <hip/hip_runtime.h>

// LightGCN forward: two gather-scale-scatter-sum propagations.
// Round 9: occupancy. Round-8 profile: gather_bkt stage-0 = 77.7us at 29%
// occupancy / 26% VALU / 31% HBM -> grid-starved latency-bound (782 blocks x
// 4 waves = 12 waves/CU). gather_bkt and partition_k widened to 512 threads
// (8 waves/block): same grids, ~2x waves/CU, LDS unchanged (33KB still allows
// 4 blocks/CU). Bucket-CSR (r7), parallel scans (r8), quad-gather (r6),
// bf16 features (r5) kept.
//
// Sizes: x [100000,128] f32; E0=1.6M edges -> 50000 dsts; E1=0.8M -> 25000.

#define DIMS 128
#define BK   64      // dsts per bucket
#define BKSH 6
#define CAP  4096    // LDS-staged edges per bucket (mean 2048, +45 sigma)
#define CH   8192    // edges per partition chunk

__device__ __forceinline__ unsigned bf16_1(float a) {
  unsigned u = __float_as_uint(a);
  return (u + 0x7fffu + ((u >> 16) & 1u)) >> 16;   // RNE
}
__device__ __forceinline__ unsigned pack_bf16(float a, float b) {
  return bf16_1(a) | (bf16_1(b) << 16);
}

// ---------------------------------------- K1: per-chunk bucket histogram + cvt
// Blocks [0, NW0+NW1): histogram chunks (stage0 then stage1).
// Blocks beyond: f32 -> bf16 conversion of x (uint4 per thread = 8 cols).
__global__ __launch_bounds__(256) void hist_cvt(
    const int* __restrict__ dst0, const int* __restrict__ dst1,
    const float* __restrict__ xf, uint4* __restrict__ xbf4,
    int* __restrict__ wgcnt0, int* __restrict__ wgcnt1,
    int E0, int E1, int NB0, int NB1, int NW0, int NW1, long long n8) {
  int b = blockIdx.x;
  if (b < NW0 + NW1) {
    __shared__ int hist[1024];
    const int s1 = (b >= NW0);
    const int w  = s1 ? b - NW0 : b;
    const int E  = s1 ? E1 : E0;
    const int NB = s1 ? NB1 : NB0;
    const int* dst = s1 ? dst1 : dst0;
    int* wgcnt = s1 ? wgcnt1 : wgcnt0;
    for (int i = threadIdx.x; i < NB; i += 256) hist[i] = 0;
    __syncthreads();
    const int beg = w * CH, end = min(beg + CH, E);
    for (int e = beg + threadIdx.x; e < end; e += 256)
      atomicAdd(&hist[dst[e] >> BKSH], 1);
    __syncthreads();
    for (int i = threadIdx.x; i < NB; i += 256)
      wgcnt[w * NB + i] = hist[i];          // [chunk][bucket] -> coalesced
  } else {
    long long t = (long long)(b - NW0 - NW1) * 256 + threadIdx.x;
    if (t < n8) {
      const float4* xf4 = (const float4*)xf;
      float4 v0 = xf4[t * 2], v1 = xf4[t * 2 + 1];
      xbf4[t] = make_uint4(pack_bf16(v0.x, v0.y), pack_bf16(v0.z, v0.w),
                           pack_bf16(v1.x, v1.y), pack_bf16(v1.z, v1.w));
    }
  }
}

// ---------------- K2a: per-bucket chunk-prefix scan. One block per bucket.
__global__ __launch_bounds__(256) void scan_cols(
    int* __restrict__ wgcnt0, int* __restrict__ wgcnt1,
    int* __restrict__ tot0, int* __restrict__ tot1,
    int NB0, int NB1, int NW0, int NW1) {
  __shared__ int part[256];
  int b = blockIdx.x;
  const int s1 = (b >= NB0);
  const int i = s1 ? b - NB0 : b;
  int* wgcnt = s1 ? wgcnt1 : wgcnt0;
  int* tot   = s1 ? tot1 : tot0;
  const int NB = s1 ? NB1 : NB0;
  const int NW = s1 ? NW1 : NW0;
  const int t = threadIdx.x;
  int v = (t < NW) ? wgcnt[t * NB + i] : 0;
  part[t] = v;
  __syncthreads();
  for (int off = 1; off < 256; off <<= 1) {
    int u = (t >= off) ? part[t - off] : 0;
    __syncthreads();
    part[t] += u;
    __syncthreads();
  }
  if (t < NW) wgcnt[t * NB + i] = part[t] - v;   // exclusive (bucket-local)
  if (t == 255) tot[i] = part[255];
}

// ---------------- K2b: bucket-total scan -> global ranges. 2 blocks.
__global__ __launch_bounds__(1024) void scan_tot(
    const int* __restrict__ tot0, const int* __restrict__ tot1,
    int2* __restrict__ rg0, int2* __restrict__ rg1, int NB0, int NB1) {
  __shared__ int part[1024];
  const int s1 = blockIdx.x;
  const int* tot = s1 ? tot1 : tot0;
  int2* rg = s1 ? rg1 : rg0;
  const int NB = s1 ? NB1 : NB0;
  const int t = threadIdx.x;
  int v = (t < NB) ? tot[t] : 0;
  part[t] = v;
  __syncthreads();
  for (int off = 1; off < 1024; off <<= 1) {
    int u = (t >= off) ? part[t - off] : 0;
    __syncthreads();
    part[t] += u;
    __syncthreads();
  }
  if (t < NB) rg[t] = make_int2(part[t] - v, part[t]);
}

// -------------------------------- K3: chunked partition into bucket regions.
// 512 threads (occupancy). Payload: x = src; y = (bf16(w) << 16) | (dst & 63).
__global__ __launch_bounds__(512) void partition_k(
    const int* __restrict__ src0, const int* __restrict__ dst0,
    const float* __restrict__ ew0, const int* __restrict__ src1,
    const int* __restrict__ dst1, const float* __restrict__ ew1,
    const int* __restrict__ wgcnt0, const int* __restrict__ wgcnt1,
    const int2* __restrict__ rg0, const int2* __restrict__ rg1,
    int2* __restrict__ payl0, int2* __restrict__ payl1,
    int E0, int E1, int NB0, int NB1, int NW0, int NW1) {
  __shared__ int cur[1024];
  int b = blockIdx.x;
  const int s1 = (b >= NW0);
  const int w  = s1 ? b - NW0 : b;
  const int E  = s1 ? E1 : E0;
  const int NB = s1 ? NB1 : NB0;
  const int* src = s1 ? src1 : src0;
  const int* dst = s1 ? dst1 : dst0;
  const float* ew = s1 ? ew1 : ew0;
  const int* wgcnt = s1 ? wgcnt1 : wgcnt0;
  const int2* rg = s1 ? rg1 : rg0;
  int2* payl = s1 ? payl1 : payl0;
  for (int i = threadIdx.x; i < NB; i += 512)
    cur[i] = rg[i].x + wgcnt[w * NB + i];
  __syncthreads();
  const int beg = w * CH, end = min(beg + CH, E);
  for (int e = beg + threadIdx.x; e < end; e += 512) {
    int d = dst[e];
    int pos = atomicAdd(&cur[d >> BKSH], 1);
    payl[pos] = make_int2(src[e],
                          (int)((bf16_1(ew[e]) << 16) | (unsigned)(d & (BK - 1))));
  }
}

// ------------------------------- K4/K5: bucket gather (one workgroup/bucket).
// 512 threads = 8 waves; each wave handles 8 of the bucket's 64 dsts.
// Counting-sort bucket edges by dst-low bits into LDS, then per-dst
// quad-register-gather: lane=(r=edge slot 0..3, c=16B chunk 0..15), uint4
// bf16 row loads, shfl_xor combine, one vector store per dst row.
template <bool OUT_BF16>
__global__ __launch_bounds__(512) void gather_bkt(
    const uint4* __restrict__ feat, const int2* __restrict__ rg,
    const int2* __restrict__ payl, void* __restrict__ outp, int n_dst) {
  __shared__ int2 lp[CAP];
  __shared__ int cnt[BK], base[BK], cnt2[BK];
  const int b = blockIdx.x;
  const int tid = threadIdx.x;
  const int2 r = rg[b];
  const int n = r.y - r.x;
  const int nin = min(n, CAP);
  if (tid < BK) { cnt[tid] = 0; cnt2[tid] = 0; }
  __syncthreads();
  for (int j = tid; j < nin; j += 512)
    atomicAdd(&cnt[payl[r.x + j].y & (BK - 1)], 1);
  __syncthreads();
  if (tid < 64) {                         // exclusive scan of cnt[64], wave 0
    int v = cnt[tid];
    int s = v;
    for (int off = 1; off < 64; off <<= 1) {
      int u = __shfl_up(s, off);
      if (tid >= off) s += u;
    }
    base[tid] = s - v;
  }
  __syncthreads();
  for (int j = tid; j < nin; j += 512) {  // place
    int2 p = payl[r.x + j];
    int dl = p.y & (BK - 1);
    int pos = base[dl] + atomicAdd(&cnt2[dl], 1);
    lp[pos] = p;
  }
  __syncthreads();
  const int wave = tid >> 6;              // 0..7
  const int lane = tid & 63;
  const int rr = lane >> 4;
  const int c  = lane & 15;
  for (int dl = wave; dl < BK; dl += 8) {
    const int row = b * BK + dl;
    if (row >= n_dst) break;              // only last bucket; monotone in dl
    const int bg = base[dl];
    const int en = bg + cnt[dl];
    float a0 = 0.f, a1 = 0.f, a2 = 0.f, a3 = 0.f;
    float a4 = 0.f, a5 = 0.f, a6 = 0.f, a7 = 0.f;
    for (int j = bg; j < en; j += 4) {
      int jj = j + rr;
      int2 p = (jj < en) ? lp[jj] : make_int2(0, 0);
      float wgt = __uint_as_float((unsigned)p.y & 0xffff0000u);
      uint4 u = feat[(size_t)p.x * 16 + c];
      a0 += __uint_as_float(u.x << 16) * wgt;
      a1 += __uint_as_float(u.x & 0xffff0000u) * wgt;
      a2 += __uint_as_float(u.y << 16) * wgt;
      a3 += __uint_as_float(u.y & 0xffff0000u) * wgt;
      a4 += __uint_as_float(u.z << 16) * wgt;
      a5 += __uint_as_float(u.z & 0xffff0000u) * wgt;
      a6 += __uint_as_float(u.w << 16) * wgt;
      a7 += __uint_as_float(u.w & 0xffff0000u) * wgt;
    }
    if (n > CAP) {                        // overflow tail (never for this input)
      for (int j = CAP; j < n; j += 4) {
        int jj = j + rr;
        int2 p = (jj < n) ? payl[r.x + jj] : make_int2(0, 0);
        bool mine = (jj < n) && ((p.y & (BK - 1)) == dl);
        float wgt = mine ? __uint_as_float((unsigned)p.y & 0xffff0000u) : 0.f;
        uint4 u = feat[(size_t)p.x * 16 + c];
        a0 += __uint_as_float(u.x << 16) * wgt;
        a1 += __uint_as_float(u.x & 0xffff0000u) * wgt;
        a2 += __uint_as_float(u.y << 16) * wgt;
        a3 += __uint_as_float(u.y & 0xffff0000u) * wgt;
        a4 += __uint_as_float(u.z << 16) * wgt;
        a5 += __uint_as_float(u.z & 0xffff0000u) * wgt;
        a6 += __uint_as_float(u.w << 16) * wgt;
        a7 += __uint_as_float(u.w & 0xffff0000u) * wgt;
      }
    }
    a0 += __shfl_xor(a0, 16); a0 += __shfl_xor(a0, 32);
    a1 += __shfl_xor(a1, 16); a1 += __shfl_xor(a1, 32);
    a2 += __shfl_xor(a2, 16); a2 += __shfl_xor(a2, 32);
    a3 += __shfl_xor(a3, 16); a3 += __shfl_xor(a3, 32);
    a4 += __shfl_xor(a4, 16); a4 += __shfl_xor(a4, 32);
    a5 += __shfl_xor(a5, 16); a5 += __shfl_xor(a5, 32);
    a6 += __shfl_xor(a6, 16); a6 += __shfl_xor(a6, 32);
    a7 += __shfl_xor(a7, 16); a7 += __shfl_xor(a7, 32);
    if (OUT_BF16) {
      if (rr == 0) {
        ((uint4*)outp)[(size_t)row * 16 + c] =
            make_uint4(pack_bf16(a0, a1), pack_bf16(a2, a3),
                       pack_bf16(a4, a5), pack_bf16(a6, a7));
      }
    } else {
      if (rr < 2) {
        ((float4*)outp)[(size_t)row * 32 + c * 2 + rr] =
            (rr == 0) ? make_float4(a0, a1, a2, a3)
                      : make_float4(a4, a5, a6, a7);
      }
    }
  }
}

// ------------------------------------------------- fallback (round-1 path)
#define COLG 32
__global__ __launch_bounds__(256) void prop_atomic(
    const float* __restrict__ x, const int* __restrict__ src,
    const int* __restrict__ dst, const float* __restrict__ ew,
    float* __restrict__ out, int E) {
  long long idx = (long long)blockIdx.x * blockDim.x + threadIdx.x;
  long long total = (long long)E * COLG;
  if (idx >= total) return;
  int e = (int)(idx >> 5);
  int cg = (int)(idx & 31);
  int s = src[e];
  int d = dst[e];
  float w = ew[e];
  const float4 v = *reinterpret_cast<const float4*>(x + (size_t)s * DIMS + cg * 4);
  float* o = out + (size_t)d * DIMS + cg * 4;
  atomicAdd(o + 0, v.x * w);
  atomicAdd(o + 1, v.y * w);
  atomicAdd(o + 2, v.z * w);
  atomicAdd(o + 3, v.w * w);
}

// --------------------------------------------------------------- launcher

static inline size_t align_up(size_t v, size_t a) { return (v + a - 1) / a * a; }

extern "C" void kernel_launch(void* const* d_in, const int* in_sizes, int n_in,
                              void* d_out, int out_size, void* d_ws, size_t ws_size,
                              hipStream_t stream) {
  const float* x    = (const float*)d_in[0];
  const int*   src0 = (const int*)d_in[1];
  const int*   dst0 = (const int*)d_in[2];
  const float* ew0  = (const float*)d_in[3];
  const int*   src1 = (const int*)d_in[4];
  const int*   dst1 = (const int*)d_in[5];
  const float* ew1  = (const float*)d_in[6];

  const int N_SRC0 = in_sizes[0] / DIMS;  // 100000
  const int E0 = in_sizes[1];             // 1600000
  const int E1 = in_sizes[4];             // 800000
  const int N_DST0 = 50000;
  const int N_DST1 = 25000;

  const int NB0 = (N_DST0 + BK - 1) / BK;   // 782
  const int NB1 = (N_DST1 + BK - 1) / BK;   // 391
  const int NW0 = (E0 + CH - 1) / CH;       // 196
  const int NW1 = (E1 + CH - 1) / CH;       // 98

  float* out = (float*)d_out;

  // --- workspace layout ---
  char* ws = (char*)d_ws;
  size_t off = 0;
  uint4* xb    = (uint4*)(ws + off); off = align_up(off + (size_t)N_SRC0 * 64 * 4, 16);
  uint4* hb    = (uint4*)(ws + off); off = align_up(off + (size_t)N_DST0 * 64 * 4, 16);
  int* wgcnt0  = (int*)(ws + off);   off = align_up(off + (size_t)NW0 * NB0 * 4, 16);
  int* wgcnt1  = (int*)(ws + off);   off = align_up(off + (size_t)NW1 * NB1 * 4, 16);
  int* tot0    = (int*)(ws + off);   off = align_up(off + (size_t)NB0 * 4, 16);
  int* tot1    = (int*)(ws + off);   off = align_up(off + (size_t)NB1 * 4, 16);
  int2* rg0    = (int2*)(ws + off);  off = align_up(off + (size_t)NB0 * 8, 16);
  int2* rg1    = (int2*)(ws + off);  off = align_up(off + (size_t)NB1 * 8, 16);
  int2* payl0  = (int2*)(ws + off);  off = align_up(off + (size_t)E0 * 8, 16);
  int2* payl1  = (int2*)(ws + off);  off = align_up(off + (size_t)E1 * 8, 16);
  const size_t needed = off;

  if (ws_size < needed) {
    float* h = (float*)d_ws;
    hipMemsetAsync(h, 0, (size_t)N_DST0 * DIMS * 4, stream);
    hipMemsetAsync(out, 0, (size_t)N_DST1 * DIMS * 4, stream);
    long long t0 = (long long)E0 * COLG;
    prop_atomic<<<(int)((t0 + 255) / 256), 256, 0, stream>>>(x, src0, dst0, ew0, h, E0);
    long long t1 = (long long)E1 * COLG;
    prop_atomic<<<(int)((t1 + 255) / 256), 256, 0, stream>>>(h, src1, dst1, ew1, out, E1);
    return;
  }

  const long long n8 = (long long)N_SRC0 * 16;   // uint4 words in xb
  const int cvtBlocks = (int)((n8 + 255) / 256);

  // K1: bucket histograms (both stages) + f32->bf16 conversion
  hist_cvt<<<NW0 + NW1 + cvtBlocks, 256, 0, stream>>>(
      dst0, dst1, x, xb, wgcnt0, wgcnt1, E0, E1, NB0, NB1, NW0, NW1, n8);

  // K2a: per-bucket chunk-prefix scan (one block per bucket, both stages)
  scan_cols<<<NB0 + NB1, 256, 0, stream>>>(wgcnt0, wgcnt1, tot0, tot1,
                                           NB0, NB1, NW0, NW1);

  // K2b: bucket-total scan -> global ranges (both stages)
  scan_tot<<<2, 1024, 0, stream>>>(tot0, tot1, rg0, rg1, NB0, NB1);

  // K3: partition edges into bucket regions (both stages)
  partition_k<<<NW0 + NW1, 512, 0, stream>>>(
      src0, dst0, ew0, src1, dst1, ew1, wgcnt0, wgcnt1, rg0, rg1,
      payl0, payl1, E0, E1, NB0, NB1, NW0, NW1);

  // K4: stage-1 gather: hb[dst0] += xb[src0] * ew0  (bf16 out)
  gather_bkt<true><<<NB0, 512, 0, stream>>>(xb, rg0, payl0, (void*)hb, N_DST0);

  // K5: stage-2 gather: out[dst1] += hb[src1] * ew1  (f32 out)
  gather_bkt<false><<<NB1, 512, 0, stream>>>(hb, rg1, payl1, (void*)out, N_DST1);
}